// Round 3
// baseline (221.616 us; speedup 1.0000x reference)
//
#include <hip/hip_runtime.h>

// Problem constants (Emformer layer)
#define T_   1024
#define B_   16
#define D_   512
#define H_   8
#define R_   32
#define S_   16
#define M_   16
#define TQ_  1072          // R + T + S
#define KL_  1072          // M + R + T
#define DH_  64            // D/H
#define NROW 17152         // TQ*B == KL*B
#define K_   512           // inner dim for ALL three GEMMs
#define LQ_  268           // KL/4 (key-quad groups)
#define QSCALE 0.18033688f // 0.125 * log2(e): folded into Q projection

typedef unsigned short u16;
using bf16x8 = __attribute__((ext_vector_type(8))) short;
using f32x4  = __attribute__((ext_vector_type(4))) float;
using u16x4  = __attribute__((ext_vector_type(4))) unsigned short;

__device__ __forceinline__ u16 f2bf(float f) {
    unsigned int u = __builtin_bit_cast(unsigned int, f);
    unsigned int r = u + 0x7fffu + ((u >> 16) & 1u);
    return (u16)(r >> 16);
}

// pack 2 f32 -> 2 bf16 in one u32 (RTNE), T12 recipe
__device__ __forceinline__ unsigned int cvt_pk_bf16(float a, float b) {
    unsigned int r;
    asm("v_cvt_pk_bf16_f32 %0, %1, %2" : "=v"(r) : "v"(a), "v"(b));
    return r;
}

// async global->LDS, 16B per lane; LDS dest = wave-uniform base + lane*16
__device__ __forceinline__ void gload_lds16(const u16* g, u16* l) {
    __builtin_amdgcn_global_load_lds(
        (const __attribute__((address_space(1))) unsigned int*)g,
        (__attribute__((address_space(3))) unsigned int*)l,
        16, 0, 0);
}

// ---------------------------------------------------------------------------
// Stage 1: single gathered buffer xall = [mems | rc | utt | smr] (17408 rows)
//   xkv = xall[0:17152], xq = xall[256:17408]
// ---------------------------------------------------------------------------
__global__ void k_convert4(const float4* __restrict__ utt, const float4* __restrict__ rc,
                           const float4* __restrict__ smr, const float4* __restrict__ mems,
                           const float4* __restrict__ Wq, const float4* __restrict__ Wkv,
                           const float4* __restrict__ Wo,
                           u16x4* __restrict__ xall,
                           u16x4* __restrict__ wq, u16x4* __restrict__ wkv,
                           u16x4* __restrict__ wo)
{
    const int N4 = 17408 * D_ / 4;
    const int MB = M_ * B_ * D_ / 4;
    const int RB = MB + R_ * B_ * D_ / 4;
    const int UB = RB + T_ * B_ * D_ / 4;
    const int W1 = D_ * D_ / 4, W2 = 2 * D_ * D_ / 4;
    for (int i = blockIdx.x * blockDim.x + threadIdx.x; i < N4;
         i += gridDim.x * blockDim.x) {
        float4 v;
        if (i < MB)      v = mems[i];
        else if (i < RB) v = rc[i - MB];
        else if (i < UB) v = utt[i - RB];
        else             v = smr[i - UB];
        xall[i] = (u16x4){f2bf(v.x), f2bf(v.y), f2bf(v.z), f2bf(v.w)};
        if (i < W1) { v = Wq[i];  wq[i]  = (u16x4){f2bf(v.x), f2bf(v.y), f2bf(v.z), f2bf(v.w)}; }
        if (i < W2) { v = Wkv[i]; wkv[i] = (u16x4){f2bf(v.x), f2bf(v.y), f2bf(v.z), f2bf(v.w)}; }
        if (i < W1) { v = Wo[i];  wo[i]  = (u16x4){f2bf(v.x), f2bf(v.y), f2bf(v.z), f2bf(v.w)}; }
    }
}

// ---------------------------------------------------------------------------
// Pipelined (2-phase, double-buffered) GEMM core. 512 threads = 8 waves,
// wave grid 2(M) x 4(N). BM = MREP*32, BN = 256, BK = 64, K = 512 (8 k-tiles).
// Next k-tile's global_load_lds issued BEFORE current tile's MFMAs; single
// __syncthreads per k-step (emits vmcnt(0) lgkmcnt(0) + s_barrier -> staged
// tile visible AND previous buffer safe to overwrite next iter).
// LDS per buffer: A BM x 64, B 256 x 64, XOR-chunk-swizzled rows (8-chunk,
// slot c^(row&7)) -- same verified scheme as before (0 bank conflicts).
//   TOR=false: acc[mi*4+ni], D rows = X-rows (quad*4+r), cols = W (col)
//   TOR=true : acc[ni*MREP+mi], D rows = W-cols (quad*4+r), cols = X-rows (col)
// ---------------------------------------------------------------------------
template<int MREP, bool TOR>
__device__ __forceinline__ void pipe_core(const u16* __restrict__ Ab,
                                          const u16* __restrict__ Wb,
                                          u16* lds, f32x4* acc)
{
    const int BM = MREP * 32;
    u16* As0 = lds;
    u16* As1 = lds + BM * 64;
    u16* Bs0 = lds + 2 * BM * 64;
    u16* Bs1 = lds + 2 * BM * 64 + 256 * 64;

    const int tid  = threadIdx.x;
    const int wid  = tid >> 6, lane = tid & 63;
    const int wm   = wid >> 2, wn = wid & 3;
    const int col  = lane & 15, quad = lane >> 4;
    const int sr   = tid >> 3;                 // 0..63 staging row within round
    const int sc   = (tid & 7) ^ (sr & 7);     // pre-swizzled source chunk
    const u16* gA  = Ab + (size_t)sr * K_ + sc * 8;
    const u16* gB  = Wb + (size_t)sr * K_ + sc * 8;

#pragma unroll
    for (int i = 0; i < MREP * 4; i++) acc[i] = (f32x4){0.f, 0.f, 0.f, 0.f};

    auto stage = [&](int kt, u16* Au, u16* Bu) {
#pragma unroll
        for (int i = 0; i < MREP / 2; i++)
            gload_lds16(gA + (size_t)(i * 64) * K_ + kt * 64,
                        Au + (i * 64 + wid * 8) * 64);
#pragma unroll
        for (int i = 0; i < 4; i++)
            gload_lds16(gB + (size_t)(i * 64) * K_ + kt * 64,
                        Bu + (i * 64 + wid * 8) * 64);
    };

    stage(0, As0, Bs0);
    __syncthreads();

    u16 *Ac = As0, *Bc = Bs0, *An = As1, *Bn = Bs1;
    for (int kt = 0; kt < 8; ++kt) {
        if (kt < 7) stage(kt + 1, An, Bn);      // prefetch next tile first
#pragma unroll
        for (int kh = 0; kh < 2; ++kh) {
            bf16x8 aF[MREP], bF[4];
#pragma unroll
            for (int mi = 0; mi < MREP; mi++)
                aF[mi] = *(const bf16x8*)&Ac[(wm * (MREP * 16) + mi * 16 + col) * 64
                             + (((kh * 4 + quad) ^ (col & 7)) * 8)];
#pragma unroll
            for (int ni = 0; ni < 4; ni++)
                bF[ni] = *(const bf16x8*)&Bc[(wn * 64 + ni * 16 + col) * 64
                             + (((kh * 4 + quad) ^ (col & 7)) * 8)];
            __builtin_amdgcn_s_setprio(1);
            if (TOR) {
#pragma unroll
                for (int ni = 0; ni < 4; ni++)
#pragma unroll
                    for (int mi = 0; mi < MREP; mi++)
                        acc[ni * MREP + mi] = __builtin_amdgcn_mfma_f32_16x16x32_bf16(
                            bF[ni], aF[mi], acc[ni * MREP + mi], 0, 0, 0);
            } else {
#pragma unroll
                for (int mi = 0; mi < MREP; mi++)
#pragma unroll
                    for (int ni = 0; ni < 4; ni++)
                        acc[mi * 4 + ni] = __builtin_amdgcn_mfma_f32_16x16x32_bf16(
                            aF[mi], bF[ni], acc[mi * 4 + ni], 0, 0, 0);
            }
            __builtin_amdgcn_s_setprio(0);
        }
        __syncthreads();   // drains prefetch (vmcnt 0) + protects buffer reuse
        u16* t;
        t = Ac; Ac = An; An = t;
        t = Bc; Bc = Bn; Bn = t;
    }
}

// ---------------------------------------------------------------------------
// Merged Q+KV projection, pipelined. Grid 67*6: tn 0,1 -> Q halves; 2,3 -> K
// halves; 4,5 -> V halves. Q/K use TOR core (8B coalesced stores); V uses
// N core (transpose-pack to vt[b][l/4][f][4]).
// ---------------------------------------------------------------------------
__global__ __launch_bounds__(512, 2)
void k_gemm_qkv8(const u16* __restrict__ xall,
                 const u16* __restrict__ wqp, const u16* __restrict__ wkvp,
                 const float* __restrict__ bq, const float* __restrict__ bkv,
                 u16* __restrict__ qb, u16* __restrict__ kb, u16* __restrict__ vt)
{
    extern __shared__ u16 lds[];
    const int bid = blockIdx.x;
    const int tn = bid % 6, tm = bid / 6;
    const int typ = tn >> 1, half = tn & 1;   // 0=Q, 1=K, 2=V
    const u16* Ab = (typ == 0 ? xall + (size_t)256 * K_ : xall)
                    + (size_t)tm * 256 * K_;
    const u16* Wb = (typ == 0 ? wqp : wkvp + (typ == 2 ? (size_t)512 * K_ : 0))
                    + (size_t)half * 256 * K_;

    const int wid = threadIdx.x >> 6, lane = threadIdx.x & 63;
    const int wm = wid >> 2, wn = wid & 3;
    const int col = lane & 15, quad = lane >> 4;

    f32x4 acc[32];
    if (typ == 2) {
        pipe_core<8, false>(Ab, Wb, lds, acc);
        // V -> vt[b][l/4][f][4]
#pragma unroll
        for (int ni = 0; ni < 4; ni++) {
            const int f = half * 256 + wn * 64 + ni * 16 + col;
            const float bs = bkv[512 + f];
#pragma unroll
            for (int mg = 0; mg < 2; mg++) {
                const int lq = tm * 4 + wm * 2 + mg;
#pragma unroll
                for (int r = 0; r < 4; r++) {
                    const int bb = quad * 4 + r;
                    uint2 pk;
                    pk.x = cvt_pk_bf16(acc[(mg * 4 + 0) * 4 + ni][r] + bs,
                                       acc[(mg * 4 + 1) * 4 + ni][r] + bs);
                    pk.y = cvt_pk_bf16(acc[(mg * 4 + 2) * 4 + ni][r] + bs,
                                       acc[(mg * 4 + 3) * 4 + ni][r] + bs);
                    *(uint2*)&vt[(((size_t)bb * LQ_ + lq) * 512 + f) * 4] = pk;
                }
            }
        }
    } else {
        pipe_core<8, true>(Ab, Wb, lds, acc);
        const float* bias = (typ == 0) ? bq : bkv;
        u16* outp = (typ == 0) ? qb : kb;
        const float qs = (typ == 0) ? QSCALE : 1.0f;
#pragma unroll
        for (int ni = 0; ni < 4; ni++) {
            const int gc0 = half * 256 + wn * 64 + ni * 16 + quad * 4;
            const float4 bs4 = *(const float4*)&bias[gc0];
#pragma unroll
            for (int mi = 0; mi < 8; mi++) {
                const int mrow = tm * 256 + wm * 128 + mi * 16 + col;
                f32x4 a = acc[ni * 8 + mi];
                uint2 pk;
                pk.x = cvt_pk_bf16((a[0] + bs4.x) * qs, (a[1] + bs4.y) * qs);
                pk.y = cvt_pk_bf16((a[2] + bs4.z) * qs, (a[3] + bs4.w) * qs);
                *(uint2*)&outp[(size_t)mrow * 512 + gc0] = pk;
            }
        }
    }
}

// ---------------------------------------------------------------------------
// Output projection + clip/slice epilogue (fp32 out), pipelined, BM=128.
// Grid 134*2. float4 coalesced stores.
// ---------------------------------------------------------------------------
__global__ __launch_bounds__(512, 2)
void k_gemm_o8(const u16* __restrict__ A, const u16* __restrict__ W,
               const float* __restrict__ bias, float* __restrict__ Co)
{
    extern __shared__ u16 lds[];
    const int tn = blockIdx.x % 2, tm = blockIdx.x / 2;   // tm 0..133
    const u16* Ab = A + (size_t)tm * 128 * K_;
    const u16* Wb = W + (size_t)tn * 256 * K_;

    const int wid = threadIdx.x >> 6, lane = threadIdx.x & 63;
    const int wm = wid >> 2, wn = wid & 3;
    const int col = lane & 15, quad = lane >> 4;

    f32x4 acc[16];
    pipe_core<4, true>(Ab, Wb, lds, acc);

#pragma unroll
    for (int ni = 0; ni < 4; ni++) {
        const int gc0 = tn * 256 + wn * 64 + ni * 16 + quad * 4;
        const float4 bs4 = *(const float4*)&bias[gc0];
#pragma unroll
        for (int mi = 0; mi < 4; mi++) {
            const int l = tm * 8 + wm * 4 + mi;
            if (l == TQ_ - 1) continue;
            const int mrow = tm * 128 + wm * 64 + mi * 16 + col;
            f32x4 a = acc[ni * 4 + mi];
            float4 v = {a[0] + bs4.x, a[1] + bs4.y, a[2] + bs4.z, a[3] + bs4.w};
            if (l >= TQ_ - S_) {
                v.x = fminf(10.0f, fmaxf(-10.0f, v.x));
                v.y = fminf(10.0f, fmaxf(-10.0f, v.y));
                v.z = fminf(10.0f, fmaxf(-10.0f, v.z));
                v.w = fminf(10.0f, fmaxf(-10.0f, v.w));
            }
            *(float4*)&Co[(size_t)mrow * 512 + gc0] = v;
        }
    }
}

// ---------------------------------------------------------------------------
// Flash attention v6: no online max (scores bounded, exp2 directly).
// PV operands swapped: o = mfma(V^T-frag, P-frag) -> d-dim lane-consecutive,
// li normalizer lane-local. cvt_pk packing throughout.
// ---------------------------------------------------------------------------
__global__ __launch_bounds__(256, 2)
void k_attn5(const u16* __restrict__ qbuf, const u16* __restrict__ kb,
             const u16* __restrict__ vt, const int* __restrict__ lenp,
             u16* __restrict__ attnb)
{
    __shared__ __align__(16) u16 Ks[2][64 * 64];
    __shared__ __align__(16) u16 Vs[2][64 * 64];
    __shared__ __align__(16) u16 Ps[4][16 * 64];

    const int blk  = blockIdx.x;
    const int qblk = 16 - (blk >> 7);       // heavy (qblk=16) first
    const int bh   = blk & 127;             // blk%8 == h -> head pinned to XCD
    const int b = bh >> 3, h = bh & 7;
    const int tid = threadIdx.x;
    const int w = tid >> 6, lane = tid & 63;
    const int col = lane & 15, quad = lane >> 4;

    int stride = (lenp[1] == 0) ? 2 : 1;
    int maxlen = 0;
    for (int i = 0; i < B_; i++) maxlen = max(maxlen, lenp[i * stride]);
    const int klen = lenp[b * stride] + M_ + (TQ_ - maxlen - S_);

    const int q0 = qblk * 64;
    const int qw = q0 + w * 16;
    const int q  = qw + col;

    int qrow = min(q, TQ_ - 1);
    const u16* qp = qbuf + ((size_t)qrow * B_ + b) * D_ + h * DH_ + quad * 8;
    bf16x8 bq0 = *(const bf16x8*)(qp);
    bf16x8 bq1 = *(const bf16x8*)(qp + 32);

    const int s0 = tid, s1 = tid + 256;
    const u16* kbase = kb + (size_t)b * 512 + h * DH_;
    size_t kof0 = (size_t)(s0 >> 3) * 8192 + (size_t)(((s0 & 7) ^ ((s0 >> 3) & 7)) * 8);
    size_t kof1 = (size_t)(s1 >> 3) * 8192 + (size_t)(((s1 & 7) ^ ((s1 >> 3) & 7)) * 8);
    const u16* vbase = vt + ((size_t)b * LQ_ * 512 + (size_t)h * DH_) * 4;
    auto vchunk = [](int s) -> size_t {
        int fp = s >> 4;
        int lq = (s & 15) ^ (fp & 15);
        return (size_t)lq * 2048 + (size_t)fp * 8;
    };
    const size_t vof0 = vchunk(s0), vof1 = vchunk(s1);

    float li = 0.f;                         // per-lane partial sum of p (q = col)
    f32x4 o[4];
#pragma unroll
    for (int g = 0; g < 4; g++) o[g] = (f32x4){0.f, 0.f, 0.f, 0.f};

    const int nk = min(q0 + 64 + M_, klen);
    const int numkt = (nk + 63) >> 6;
    u16* pw = &Ps[w][0];

    gload_lds16(kbase + kof0, &Ks[0][(size_t)w * 512]);
    gload_lds16(kbase + kof1, &Ks[0][2048 + (size_t)w * 512]);
    gload_lds16(vbase + vof0, &Vs[0][(size_t)w * 512]);
    gload_lds16(vbase + vof1, &Vs[0][2048 + (size_t)w * 512]);

    for (int kt = 0; kt < numkt; kt++) {
        const int kn0 = kt * 64;
        const int cur = kt & 1;
        __syncthreads();
        if (kt + 1 < numkt) {
            const size_t kstep = (size_t)(kn0 + 64) * 8192;
            const size_t vstep = (size_t)(kt + 1) * 32768;
            gload_lds16(kbase + kstep + kof0, &Ks[cur ^ 1][(size_t)w * 512]);
            gload_lds16(kbase + kstep + kof1, &Ks[cur ^ 1][2048 + (size_t)w * 512]);
            gload_lds16(vbase + vstep + vof0, &Vs[cur ^ 1][(size_t)w * 512]);
            gload_lds16(vbase + vstep + vof1, &Vs[cur ^ 1][2048 + (size_t)w * 512]);
        }

        // QK^T (Q pre-scaled into exp2 domain): sc[g][r] = S[kn0+g*16+quad*4+r][q=col]
        f32x4 sc[4];
        __builtin_amdgcn_s_setprio(1);
#pragma unroll
        for (int g = 0; g < 4; g++) {
            int key = g * 16 + col;
            bf16x8 a0 = *(const bf16x8*)&Ks[cur][key * 64 + ((quad ^ (key & 7)) * 8)];
            bf16x8 a1 = *(const bf16x8*)&Ks[cur][key * 64 + (((4 + quad) ^ (key & 7)) * 8)];
            f32x4 z = {0.f, 0.f, 0.f, 0.f};
            z = __builtin_amdgcn_mfma_f32_16x16x32_bf16(a0, bq0, z, 0, 0, 0);
            z = __builtin_amdgcn_mfma_f32_16x16x32_bf16(a1, bq1, z, 0, 0, 0);
            sc[g] = z;
        }
        __builtin_amdgcn_s_setprio(0);

        // boundary-only masking
        const bool needmask = (kn0 + 63 > qw + M_) || (kn0 + 63 >= klen);
        if (needmask) {
#pragma unroll
            for (int g = 0; g < 4; g++)
#pragma unroll
                for (int r = 0; r < 4; r++) {
                    int key = kn0 + g * 16 + quad * 4 + r;
                    bool valid = (key <= q + M_) && (key < klen);
                    sc[g][r] = valid ? sc[g][r] : -1e8f;
                }
        }

        // p = exp2(s): local sum, cvt_pk pack to LDS (P[q=col][key])
#pragma unroll
        for (int g = 0; g < 4; g++) {
            float pr[4];
#pragma unroll
            for (int r = 0; r < 4; r++) {
                pr[r] = __builtin_amdgcn_exp2f(sc[g][r]);
                li += pr[r];
            }
            uint2 pk;
            pk.x = cvt_pk_bf16(pr[0], pr[1]);
            pk.y = cvt_pk_bf16(pr[2], pr[3]);
            int kc = g * 2 + (quad >> 1);
            *(uint2*)&pw[col * 64 + ((kc ^ (col & 7)) * 8) + (quad & 1) * 4] = pk;
        }

        // PV swapped: A = V^T-frag (m=d), B = P-frag (n=q); D[d][q]
        bf16x8 ap0 = *(const bf16x8*)&pw[col * 64 + ((quad ^ (col & 7)) * 8)];
        bf16x8 ap1 = *(const bf16x8*)&pw[col * 64 + (((4 + quad) ^ (col & 7)) * 8)];
        __builtin_amdgcn_s_setprio(1);
#pragma unroll
        for (int g = 0; g < 4; g++) {
            int d = g * 16 + col;
            int fp = d >> 1, fo = (d & 1) * 4;
            bf16x8 bv[2];
#pragma unroll
            for (int hh = 0; hh < 2; hh++) {
                int lqA = hh * 8 + quad * 2;
                int posA = fp * 16 + (lqA ^ (fp & 15));
                int posB = fp * 16 + ((lqA + 1) ^ (fp & 15));
                u16x4 loA = *(const u16x4*)&Vs[cur][posA * 8 + fo];
                u16x4 loB = *(const u16x4*)&Vs[cur][posB * 8 + fo];
                bf16x8 t;
                t[0] = loA[0]; t[1] = loA[1]; t[2] = loA[2]; t[3] = loA[3];
                t[4] = loB[0]; t[5] = loB[1]; t[6] = loB[2]; t[7] = loB[3];
                bv[hh] = t;
            }
            o[g] = __builtin_amdgcn_mfma_f32_16x16x32_bf16(bv[0], ap0, o[g], 0, 0, 0);
            o[g] = __builtin_amdgcn_mfma_f32_16x16x32_bf16(bv[1], ap1, o[g], 0, 0, 0);
        }
        __builtin_amdgcn_s_setprio(0);
    }

    // l reduction across quads; q = col is lane-local so inv applies directly
    li += __shfl_xor(li, 16);
    li += __shfl_xor(li, 32);
    const float inv = 1.0f / li;
    const int qo = qw + col;
    if (qw + 16 <= TQ_) {
#pragma unroll
        for (int g = 0; g < 4; g++) {
            uint2 pk;
            pk.x = cvt_pk_bf16(o[g][0] * inv, o[g][1] * inv);
            pk.y = cvt_pk_bf16(o[g][2] * inv, o[g][3] * inv);
            *(uint2*)&attnb[((size_t)qo * B_ + b) * D_ + h * DH_ + g * 16 + quad * 4] = pk;
        }
    }
}

// ---------------------------------------------------------------------------
extern "C" void kernel_launch(void* const* d_in, const int* in_sizes, int n_in,
                              void* d_out, int out_size, void* d_ws, size_t ws_size,
                              hipStream_t stream)
{
    const float* utt  = (const float*)d_in[0];
    const int*   len  = (const int*)  d_in[1];
    const float* rc   = (const float*)d_in[2];
    const float* smr  = (const float*)d_in[3];
    const float* mems = (const float*)d_in[4];
    const float* Wq   = (const float*)d_in[6];
    const float* bq   = (const float*)d_in[7];
    const float* Wkv  = (const float*)d_in[8];
    const float* bkv  = (const float*)d_in[9];
    const float* Wo   = (const float*)d_in[10];
    const float* bo   = (const float*)d_in[11];

    char* ws = (char*)d_ws;
    size_t off = 0;
    auto alloc = [&](size_t bytes) -> void* {
        void* p = ws + off;
        off += (bytes + 255) & ~(size_t)255;
        return p;
    };
    u16* xall = (u16*)alloc((size_t)17408 * D_ * 2);
    u16* wq   = (u16*)alloc((size_t)D_ * D_ * 2);
    u16* wkv  = (u16*)alloc((size_t)2 * D_ * D_ * 2);
    u16* wo   = (u16*)alloc((size_t)D_ * D_ * 2);
    u16* qb   = (u16*)alloc((size_t)NROW * D_ * 2);
    u16* kb   = (u16*)alloc((size_t)NROW * D_ * 2);
    u16* vt   = (u16*)alloc((size_t)B_ * LQ_ * 512 * 4 * 2 + 65536);
    u16* attnb = xall;  // xall dead after QKV-GEMM

    static int s_attr_done = 0;
    if (!s_attr_done) {
        hipFuncSetAttribute(reinterpret_cast<const void*>(k_gemm_qkv8),
                            hipFuncAttributeMaxDynamicSharedMemorySize, 131072);
        hipFuncSetAttribute(reinterpret_cast<const void*>(k_gemm_o8),
                            hipFuncAttributeMaxDynamicSharedMemorySize, 98304);
        s_attr_done = 1;
    }

    k_convert4<<<2048, 256, 0, stream>>>((const float4*)utt, (const float4*)rc,
                                         (const float4*)smr, (const float4*)mems,
                                         (const float4*)Wq, (const float4*)Wkv,
                                         (const float4*)Wo,
                                         (u16x4*)xall,
                                         (u16x4*)wq, (u16x4*)wkv, (u16x4*)wo);
    k_gemm_qkv8<<<67 * 6, 512, 131072, stream>>>(xall, wq, wkv, bq, bkv, qb, kb, vt);
    k_attn5<<<17 * 128, 256, 0, stream>>>(qb, kb, vt, len, attnb);
    k_gemm_o8<<<134 * 2, 512, 98304, stream>>>(attnb, wo, bo, (float*)d_out);
}

// Round 5
// 217.154 us; speedup vs baseline: 1.0205x; 1.0205x over previous
//
#include <hip/hip_runtime.h>

// Problem constants (Emformer layer)
#define T_   1024
#define B_   16
#define D_   512
#define H_   8
#define R_   32
#define S_   16
#define M_   16
#define TQ_  1072          // R + T + S
#define KL_  1072          // M + R + T
#define DH_  64            // D/H
#define NROW 17152         // TQ*B == KL*B
#define K_   512           // inner dim for ALL three GEMMs
#define LQ_  268           // KL/4 (key-quad groups)
#define QSCALE 0.18033688f // 0.125 * log2(e): folded into Q projection

typedef unsigned short u16;
using bf16x8 = __attribute__((ext_vector_type(8))) short;
using f32x4  = __attribute__((ext_vector_type(4))) float;
using u16x4  = __attribute__((ext_vector_type(4))) unsigned short;

__device__ __forceinline__ u16 f2bf(float f) {
    unsigned int u = __builtin_bit_cast(unsigned int, f);
    unsigned int r = u + 0x7fffu + ((u >> 16) & 1u);
    return (u16)(r >> 16);
}

// pack 2 f32 -> 2 bf16 in one u32 (RTNE), T12 recipe
__device__ __forceinline__ unsigned int cvt_pk_bf16(float a, float b) {
    unsigned int r;
    asm("v_cvt_pk_bf16_f32 %0, %1, %2" : "=v"(r) : "v"(a), "v"(b));
    return r;
}

// async global->LDS, 16B per lane; LDS dest = wave-uniform base + lane*16
__device__ __forceinline__ void gload_lds16(const u16* g, u16* l) {
    __builtin_amdgcn_global_load_lds(
        (const __attribute__((address_space(1))) unsigned int*)g,
        (__attribute__((address_space(3))) unsigned int*)l,
        16, 0, 0);
}

// bijective XCD swizzle (m204): hw bid -> logical wgid; same-XCD bids get a
// contiguous logical range so L2-shared operands stay on one XCD.
__device__ __forceinline__ int xcd_swz(int bid, int nwg) {
    const int q = nwg >> 3, r = nwg & 7;
    const int xcd = bid & 7, idx = bid >> 3;
    return (xcd < r ? xcd * (q + 1) : r * (q + 1) + (xcd - r) * q) + idx;
}

// ---------------------------------------------------------------------------
// Stage 1: single gathered buffer xall = [mems | rc | utt | smr] (17408 rows)
//   xkv = xall[0:17152], xq = xall[256:17408]
// ---------------------------------------------------------------------------
__global__ void k_convert4(const float4* __restrict__ utt, const float4* __restrict__ rc,
                           const float4* __restrict__ smr, const float4* __restrict__ mems,
                           const float4* __restrict__ Wq, const float4* __restrict__ Wkv,
                           const float4* __restrict__ Wo,
                           u16x4* __restrict__ xall,
                           u16x4* __restrict__ wq, u16x4* __restrict__ wkv,
                           u16x4* __restrict__ wo)
{
    const int N4 = 17408 * D_ / 4;
    const int MB = M_ * B_ * D_ / 4;
    const int RB = MB + R_ * B_ * D_ / 4;
    const int UB = RB + T_ * B_ * D_ / 4;
    const int W1 = D_ * D_ / 4, W2 = 2 * D_ * D_ / 4;
    for (int i = blockIdx.x * blockDim.x + threadIdx.x; i < N4;
         i += gridDim.x * blockDim.x) {
        float4 v;
        if (i < MB)      v = mems[i];
        else if (i < RB) v = rc[i - MB];
        else if (i < UB) v = utt[i - RB];
        else             v = smr[i - UB];
        xall[i] = (u16x4){f2bf(v.x), f2bf(v.y), f2bf(v.z), f2bf(v.w)};
        if (i < W1) { v = Wq[i];  wq[i]  = (u16x4){f2bf(v.x), f2bf(v.y), f2bf(v.z), f2bf(v.w)}; }
        if (i < W2) { v = Wkv[i]; wkv[i] = (u16x4){f2bf(v.x), f2bf(v.y), f2bf(v.z), f2bf(v.w)}; }
        if (i < W1) { v = Wo[i];  wo[i]  = (u16x4){f2bf(v.x), f2bf(v.y), f2bf(v.z), f2bf(v.w)}; }
    }
}

// ---------------------------------------------------------------------------
// Counted-vmcnt double-buffered GEMM core (T4). 512 threads = 8 waves,
// wave grid 4(M) x 2(N); BM=256, BN=128, BK=64, K=512 (8 k-tiles).
// Per k-step:
//   s_barrier                      (a) all waves done READING the buffer we
//                                      are about to overwrite
//   stage(t+1) -> other buffer     6 gload_lds per wave, stay in flight
//   s_waitcnt vmcnt(6)             waits ONLY for tile t's 6 loads (FIFO)
//   s_barrier                      (b) tile t visible to all waves
//   ds_read frags + MFMA           compiler emits its own lgkmcnt waits
// No vmcnt(0) drain in the main loop -- the T4 property (m218: +38..73%
// vs drain-0). LDS: (256+128)x64x2B x2buf = 96 KB, XOR-chunk swizzle
// (slot c^(row&7), verified 0 bank conflicts).
//   TOR=false: acc[mi*4+ni] = mfma(aF,bF): D rows = X-rows (quad*4+r)
//   TOR=true : acc[ni*4+mi] = mfma(bF,aF): D rows = W-cols (quad*4+r)
// ---------------------------------------------------------------------------
template<bool TOR>
__device__ __forceinline__ void pipe_core(const u16* __restrict__ Ab,
                                          const u16* __restrict__ Wb,
                                          u16* lds, f32x4* acc)
{
    u16* As0 = lds;                    // 256*64
    u16* As1 = lds + 256 * 64;
    u16* Bs0 = lds + 2 * 256 * 64;     // 128*64
    u16* Bs1 = lds + 2 * 256 * 64 + 128 * 64;

    const int tid  = threadIdx.x;
    const int wid  = tid >> 6, lane = tid & 63;
    const int wm   = wid >> 1, wn = wid & 1;
    const int col  = lane & 15, quad = lane >> 4;
    const int sr   = tid >> 3;                 // 0..63 staging row in round
    const int sc   = (tid & 7) ^ (sr & 7);     // pre-swizzled source chunk
    const u16* gA  = Ab + (size_t)sr * K_ + sc * 8;
    const u16* gB  = Wb + (size_t)sr * K_ + sc * 8;

#pragma unroll
    for (int i = 0; i < 16; i++) acc[i] = (f32x4){0.f, 0.f, 0.f, 0.f};

    auto stage = [&](int kt, u16* Au, u16* Bu) {
#pragma unroll
        for (int i = 0; i < 4; i++)            // A: 256 rows, 4 rounds of 64
            gload_lds16(gA + (size_t)(i * 64) * K_ + kt * 64,
                        Au + (i * 64 + wid * 8) * 64);
#pragma unroll
        for (int j = 0; j < 2; j++)            // B: 128 rows, 2 rounds of 64
            gload_lds16(gB + (size_t)(j * 64) * K_ + kt * 64,
                        Bu + (j * 64 + wid * 8) * 64);
    };

    stage(0, As0, Bs0);

    u16 *Ac = As0, *Bc = Bs0, *An = As1, *Bn = Bs1;
    for (int kt = 0; kt < 8; ++kt) {
        __builtin_amdgcn_s_barrier();              // (a)
        if (kt < 7) {
            stage(kt + 1, An, Bn);
            asm volatile("s_waitcnt vmcnt(6)" ::: "memory");
        } else {
            asm volatile("s_waitcnt vmcnt(0)" ::: "memory");
        }
        __builtin_amdgcn_s_barrier();              // (b)
        __builtin_amdgcn_sched_barrier(0);
#pragma unroll
        for (int kh = 0; kh < 2; ++kh) {
            bf16x8 aF[4], bF[4];
#pragma unroll
            for (int mi = 0; mi < 4; mi++)
                aF[mi] = *(const bf16x8*)&Ac[(wm * 64 + mi * 16 + col) * 64
                             + (((kh * 4 + quad) ^ (col & 7)) * 8)];
#pragma unroll
            for (int ni = 0; ni < 4; ni++)
                bF[ni] = *(const bf16x8*)&Bc[(wn * 64 + ni * 16 + col) * 64
                             + (((kh * 4 + quad) ^ (col & 7)) * 8)];
            __builtin_amdgcn_s_setprio(1);
            if (TOR) {
#pragma unroll
                for (int ni = 0; ni < 4; ni++)
#pragma unroll
                    for (int mi = 0; mi < 4; mi++)
                        acc[ni * 4 + mi] = __builtin_amdgcn_mfma_f32_16x16x32_bf16(
                            bF[ni], aF[mi], acc[ni * 4 + mi], 0, 0, 0);
            } else {
#pragma unroll
                for (int mi = 0; mi < 4; mi++)
#pragma unroll
                    for (int ni = 0; ni < 4; ni++)
                        acc[mi * 4 + ni] = __builtin_amdgcn_mfma_f32_16x16x32_bf16(
                            aF[mi], bF[ni], acc[mi * 4 + ni], 0, 0, 0);
            }
            __builtin_amdgcn_s_setprio(0);
        }
        u16* t;
        t = Ac; Ac = An; An = t;
        t = Bc; Bc = Bn; Bn = t;
    }
}

// ---------------------------------------------------------------------------
// Merged Q+KV projection. Logical wgid (XCD-swizzled, tn-minor so one XCD
// reuses each A-tile 12x from its own L2): tn 0..3 -> Q, 4..7 -> K,
// 8..11 -> V; tm 0..66. Q/K: TOR core, 8B coalesced stores; V: N core,
// transpose-pack to vt[b][l/4][f][4].
// ---------------------------------------------------------------------------
__global__ __launch_bounds__(512, 2)
void k_gemm_qkv8(const u16* __restrict__ xall,
                 const u16* __restrict__ wqp, const u16* __restrict__ wkvp,
                 const float* __restrict__ bq, const float* __restrict__ bkv,
                 u16* __restrict__ qb, u16* __restrict__ kb, u16* __restrict__ vt)
{
    extern __shared__ u16 lds[];
    const int wgid = xcd_swz(blockIdx.x, 67 * 12);
    const int tn = wgid % 12, tm = wgid / 12;
    const int typ = tn >> 2, sub = tn & 3;    // 0=Q, 1=K, 2=V
    const u16* Ab = (typ == 0 ? xall + (size_t)256 * K_ : xall)
                    + (size_t)tm * 256 * K_;
    const u16* Wb = (typ == 0 ? wqp : wkvp + (typ == 2 ? (size_t)512 * K_ : 0))
                    + (size_t)sub * 128 * K_;

    const int wid = threadIdx.x >> 6, lane = threadIdx.x & 63;
    const int wm = wid >> 1, wn = wid & 1;
    const int col = lane & 15, quad = lane >> 4;

    f32x4 acc[16];
    if (typ == 2) {
        pipe_core<false>(Ab, Wb, lds, acc);
        // V -> vt[b][l/4][f][4]; l = tm*16 + wm*4 + mi, b = quad*4+r
#pragma unroll
        for (int ni = 0; ni < 4; ni++) {
            const int f = sub * 128 + wn * 64 + ni * 16 + col;
            const float bs = bkv[512 + f];
            const int lq = tm * 4 + wm;
#pragma unroll
            for (int r = 0; r < 4; r++) {
                const int bb = quad * 4 + r;
                uint2 pk;
                pk.x = cvt_pk_bf16(acc[0 * 4 + ni][r] + bs,
                                   acc[1 * 4 + ni][r] + bs);
                pk.y = cvt_pk_bf16(acc[2 * 4 + ni][r] + bs,
                                   acc[3 * 4 + ni][r] + bs);
                *(uint2*)&vt[(((size_t)bb * LQ_ + lq) * 512 + f) * 4] = pk;
            }
        }
    } else {
        pipe_core<true>(Ab, Wb, lds, acc);
        const float* bias = (typ == 0) ? bq : bkv;
        u16* outp = (typ == 0) ? qb : kb;
        const float qs = (typ == 0) ? QSCALE : 1.0f;
#pragma unroll
        for (int ni = 0; ni < 4; ni++) {
            const int gc0 = sub * 128 + wn * 64 + ni * 16 + quad * 4;
            const float4 bs4 = *(const float4*)&bias[gc0];
#pragma unroll
            for (int mi = 0; mi < 4; mi++) {
                const int mrow = tm * 256 + wm * 64 + mi * 16 + col;
                f32x4 a = acc[ni * 4 + mi];
                uint2 pk;
                pk.x = cvt_pk_bf16((a[0] + bs4.x) * qs, (a[1] + bs4.y) * qs);
                pk.y = cvt_pk_bf16((a[2] + bs4.z) * qs, (a[3] + bs4.w) * qs);
                *(uint2*)&outp[(size_t)mrow * 512 + gc0] = pk;
            }
        }
    }
}

// ---------------------------------------------------------------------------
// Output projection + clip/slice epilogue (fp32 out), TOR core, float4 stores.
// Logical wgid: tn 0..3 (128-col tiles), tm 0..66.
// ---------------------------------------------------------------------------
__global__ __launch_bounds__(512, 2)
void k_gemm_o8(const u16* __restrict__ A, const u16* __restrict__ W,
               const float* __restrict__ bias, float* __restrict__ Co)
{
    extern __shared__ u16 lds[];
    const int wgid = xcd_swz(blockIdx.x, 67 * 4);
    const int tn = wgid % 4, tm = wgid / 4;
    const u16* Ab = A + (size_t)tm * 256 * K_;
    const u16* Wb = W + (size_t)tn * 128 * K_;

    const int wid = threadIdx.x >> 6, lane = threadIdx.x & 63;
    const int wm = wid >> 1, wn = wid & 1;
    const int col = lane & 15, quad = lane >> 4;

    f32x4 acc[16];
    pipe_core<true>(Ab, Wb, lds, acc);

#pragma unroll
    for (int ni = 0; ni < 4; ni++) {
        const int gc0 = tn * 128 + wn * 64 + ni * 16 + quad * 4;
        const float4 bs4 = *(const float4*)&bias[gc0];
#pragma unroll
        for (int mi = 0; mi < 4; mi++) {
            const int l = tm * 16 + wm * 4 + mi;
            if (l == TQ_ - 1) continue;
            const int mrow = tm * 256 + wm * 64 + mi * 16 + col;
            f32x4 a = acc[ni * 4 + mi];
            float4 v = {a[0] + bs4.x, a[1] + bs4.y, a[2] + bs4.z, a[3] + bs4.w};
            if (l >= TQ_ - S_) {
                v.x = fminf(10.0f, fmaxf(-10.0f, v.x));
                v.y = fminf(10.0f, fmaxf(-10.0f, v.y));
                v.z = fminf(10.0f, fmaxf(-10.0f, v.z));
                v.w = fminf(10.0f, fmaxf(-10.0f, v.w));
            }
            *(float4*)&Co[(size_t)mrow * 512 + gc0] = v;
        }
    }
}

// ---------------------------------------------------------------------------
// Flash attention v6: no online max (scores bounded, exp2 directly).
// PV operands swapped: o = mfma(V^T-frag, P-frag) -> d-dim lane-consecutive,
// li normalizer lane-local. cvt_pk packing throughout.
// ---------------------------------------------------------------------------
__global__ __launch_bounds__(256, 2)
void k_attn5(const u16* __restrict__ qbuf, const u16* __restrict__ kb,
             const u16* __restrict__ vt, const int* __restrict__ lenp,
             u16* __restrict__ attnb)
{
    __shared__ __align__(16) u16 Ks[2][64 * 64];
    __shared__ __align__(16) u16 Vs[2][64 * 64];
    __shared__ __align__(16) u16 Ps[4][16 * 64];

    const int blk  = blockIdx.x;
    const int qblk = 16 - (blk >> 7);       // heavy (qblk=16) first
    const int bh   = blk & 127;             // blk%8 == h -> head pinned to XCD
    const int b = bh >> 3, h = bh & 7;
    const int tid = threadIdx.x;
    const int w = tid >> 6, lane = tid & 63;
    const int col = lane & 15, quad = lane >> 4;

    int stride = (lenp[1] == 0) ? 2 : 1;
    int maxlen = 0;
    for (int i = 0; i < B_; i++) maxlen = max(maxlen, lenp[i * stride]);
    const int klen = lenp[b * stride] + M_ + (TQ_ - maxlen - S_);

    const int q0 = qblk * 64;
    const int qw = q0 + w * 16;
    const int q  = qw + col;

    int qrow = min(q, TQ_ - 1);
    const u16* qp = qbuf + ((size_t)qrow * B_ + b) * D_ + h * DH_ + quad * 8;
    bf16x8 bq0 = *(const bf16x8*)(qp);
    bf16x8 bq1 = *(const bf16x8*)(qp + 32);

    const int s0 = tid, s1 = tid + 256;
    const u16* kbase = kb + (size_t)b * 512 + h * DH_;
    size_t kof0 = (size_t)(s0 >> 3) * 8192 + (size_t)(((s0 & 7) ^ ((s0 >> 3) & 7)) * 8);
    size_t kof1 = (size_t)(s1 >> 3) * 8192 + (size_t)(((s1 & 7) ^ ((s1 >> 3) & 7)) * 8);
    const u16* vbase = vt + ((size_t)b * LQ_ * 512 + (size_t)h * DH_) * 4;
    auto vchunk = [](int s) -> size_t {
        int fp = s >> 4;
        int lq = (s & 15) ^ (fp & 15);
        return (size_t)lq * 2048 + (size_t)fp * 8;
    };
    const size_t vof0 = vchunk(s0), vof1 = vchunk(s1);

    float li = 0.f;                         // per-lane partial sum of p (q = col)
    f32x4 o[4];
#pragma unroll
    for (int g = 0; g < 4; g++) o[g] = (f32x4){0.f, 0.f, 0.f, 0.f};

    const int nk = min(q0 + 64 + M_, klen);
    const int numkt = (nk + 63) >> 6;
    u16* pw = &Ps[w][0];

    gload_lds16(kbase + kof0, &Ks[0][(size_t)w * 512]);
    gload_lds16(kbase + kof1, &Ks[0][2048 + (size_t)w * 512]);
    gload_lds16(vbase + vof0, &Vs[0][(size_t)w * 512]);
    gload_lds16(vbase + vof1, &Vs[0][2048 + (size_t)w * 512]);

    for (int kt = 0; kt < numkt; kt++) {
        const int kn0 = kt * 64;
        const int cur = kt & 1;
        __syncthreads();
        if (kt + 1 < numkt) {
            const size_t kstep = (size_t)(kn0 + 64) * 8192;
            const size_t vstep = (size_t)(kt + 1) * 32768;
            gload_lds16(kbase + kstep + kof0, &Ks[cur ^ 1][(size_t)w * 512]);
            gload_lds16(kbase + kstep + kof1, &Ks[cur ^ 1][2048 + (size_t)w * 512]);
            gload_lds16(vbase + vstep + vof0, &Vs[cur ^ 1][(size_t)w * 512]);
            gload_lds16(vbase + vstep + vof1, &Vs[cur ^ 1][2048 + (size_t)w * 512]);
        }

        // QK^T (Q pre-scaled into exp2 domain): sc[g][r] = S[kn0+g*16+quad*4+r][q=col]
        f32x4 sc[4];
        __builtin_amdgcn_s_setprio(1);
#pragma unroll
        for (int g = 0; g < 4; g++) {
            int key = g * 16 + col;
            bf16x8 a0 = *(const bf16x8*)&Ks[cur][key * 64 + ((quad ^ (key & 7)) * 8)];
            bf16x8 a1 = *(const bf16x8*)&Ks[cur][key * 64 + (((4 + quad) ^ (key & 7)) * 8)];
            f32x4 z = {0.f, 0.f, 0.f, 0.f};
            z = __builtin_amdgcn_mfma_f32_16x16x32_bf16(a0, bq0, z, 0, 0, 0);
            z = __builtin_amdgcn_mfma_f32_16x16x32_bf16(a1, bq1, z, 0, 0, 0);
            sc[g] = z;
        }
        __builtin_amdgcn_s_setprio(0);

        // boundary-only masking
        const bool needmask = (kn0 + 63 > qw + M_) || (kn0 + 63 >= klen);
        if (needmask) {
#pragma unroll
            for (int g = 0; g < 4; g++)
#pragma unroll
                for (int r = 0; r < 4; r++) {
                    int key = kn0 + g * 16 + quad * 4 + r;
                    bool valid = (key <= q + M_) && (key < klen);
                    sc[g][r] = valid ? sc[g][r] : -1e8f;
                }
        }

        // p = exp2(s): local sum, cvt_pk pack to LDS (P[q=col][key])
#pragma unroll
        for (int g = 0; g < 4; g++) {
            float pr[4];
#pragma unroll
            for (int r = 0; r < 4; r++) {
                pr[r] = __builtin_amdgcn_exp2f(sc[g][r]);
                li += pr[r];
            }
            uint2 pk;
            pk.x = cvt_pk_bf16(pr[0], pr[1]);
            pk.y = cvt_pk_bf16(pr[2], pr[3]);
            int kc = g * 2 + (quad >> 1);
            *(uint2*)&pw[col * 64 + ((kc ^ (col & 7)) * 8) + (quad & 1) * 4] = pk;
        }

        // PV swapped: A = V^T-frag (m=d), B = P-frag (n=q); D[d][q]
        bf16x8 ap0 = *(const bf16x8*)&pw[col * 64 + ((quad ^ (col & 7)) * 8)];
        bf16x8 ap1 = *(const bf16x8*)&pw[col * 64 + (((4 + quad) ^ (col & 7)) * 8)];
        __builtin_amdgcn_s_setprio(1);
#pragma unroll
        for (int g = 0; g < 4; g++) {
            int d = g * 16 + col;
            int fp = d >> 1, fo = (d & 1) * 4;
            bf16x8 bv[2];
#pragma unroll
            for (int hh = 0; hh < 2; hh++) {
                int lqA = hh * 8 + quad * 2;
                int posA = fp * 16 + (lqA ^ (fp & 15));
                int posB = fp * 16 + ((lqA + 1) ^ (fp & 15));
                u16x4 loA = *(const u16x4*)&Vs[cur][posA * 8 + fo];
                u16x4 loB = *(const u16x4*)&Vs[cur][posB * 8 + fo];
                bf16x8 t;
                t[0] = loA[0]; t[1] = loA[1]; t[2] = loA[2]; t[3] = loA[3];
                t[4] = loB[0]; t[5] = loB[1]; t[6] = loB[2]; t[7] = loB[3];
                bv[hh] = t;
            }
            o[g] = __builtin_amdgcn_mfma_f32_16x16x32_bf16(bv[0], ap0, o[g], 0, 0, 0);
            o[g] = __builtin_amdgcn_mfma_f32_16x16x32_bf16(bv[1], ap1, o[g], 0, 0, 0);
        }
        __builtin_amdgcn_s_setprio(0);
    }

    // l reduction across quads; q = col is lane-local so inv applies directly
    li += __shfl_xor(li, 16);
    li += __shfl_xor(li, 32);
    const float inv = 1.0f / li;
    const int qo = qw + col;
    if (qw + 16 <= TQ_) {
#pragma unroll
        for (int g = 0; g < 4; g++) {
            uint2 pk;
            pk.x = cvt_pk_bf16(o[g][0] * inv, o[g][1] * inv);
            pk.y = cvt_pk_bf16(o[g][2] * inv, o[g][3] * inv);
            *(uint2*)&attnb[((size_t)qo * B_ + b) * D_ + h * DH_ + g * 16 + quad * 4] = pk;
        }
    }
}

// ---------------------------------------------------------------------------
extern "C" void kernel_launch(void* const* d_in, const int* in_sizes, int n_in,
                              void* d_out, int out_size, void* d_ws, size_t ws_size,
                              hipStream_t stream)
{
    const float* utt  = (const float*)d_in[0];
    const int*   len  = (const int*)  d_in[1];
    const float* rc   = (const float*)d_in[2];
    const float* smr  = (const float*)d_in[3];
    const float* mems = (const float*)d_in[4];
    const float* Wq   = (const float*)d_in[6];
    const float* bq   = (const float*)d_in[7];
    const float* Wkv  = (const float*)d_in[8];
    const float* bkv  = (const float*)d_in[9];
    const float* Wo   = (const float*)d_in[10];
    const float* bo   = (const float*)d_in[11];

    char* ws = (char*)d_ws;
    size_t off = 0;
    auto alloc = [&](size_t bytes) -> void* {
        void* p = ws + off;
        off += (bytes + 255) & ~(size_t)255;
        return p;
    };
    u16* xall = (u16*)alloc((size_t)17408 * D_ * 2);
    u16* wq   = (u16*)alloc((size_t)D_ * D_ * 2);
    u16* wkv  = (u16*)alloc((size_t)2 * D_ * D_ * 2);
    u16* wo   = (u16*)alloc((size_t)D_ * D_ * 2);
    u16* qb   = (u16*)alloc((size_t)NROW * D_ * 2);
    u16* kb   = (u16*)alloc((size_t)NROW * D_ * 2);
    u16* vt   = (u16*)alloc((size_t)B_ * LQ_ * 512 * 4 * 2 + 65536);
    u16* attnb = xall;  // xall dead after QKV-GEMM

    static int s_attr_done = 0;
    if (!s_attr_done) {
        hipFuncSetAttribute(reinterpret_cast<const void*>(k_gemm_qkv8),
                            hipFuncAttributeMaxDynamicSharedMemorySize, 98304);
        hipFuncSetAttribute(reinterpret_cast<const void*>(k_gemm_o8),
                            hipFuncAttributeMaxDynamicSharedMemorySize, 98304);
        s_attr_done = 1;
    }

    k_convert4<<<2048, 256, 0, stream>>>((const float4*)utt, (const float4*)rc,
                                         (const float4*)smr, (const float4*)mems,
                                         (const float4*)Wq, (const float4*)Wkv,
                                         (const float4*)Wo,
                                         (u16x4*)xall,
                                         (u16x4*)wq, (u16x4*)wkv, (u16x4*)wo);
    k_gemm_qkv8<<<67 * 12, 512, 98304, stream>>>(xall, wq, wkv, bq, bkv, qb, kb, vt);
    k_attn5<<<17 * 128, 256, 0, stream>>>(qb, kb, vt, len, attnb);
    k_gemm_o8<<<67 * 4, 512, 98304, stream>>>(attnb, wo, bo, (float*)d_out);
}

// Round 6
// 215.876 us; speedup vs baseline: 1.0266x; 1.0059x over previous
//
#include <hip/hip_runtime.h>

// Problem constants (Emformer layer)
#define T_   1024
#define B_   16
#define D_   512
#define H_   8
#define R_   32
#define S_   16
#define M_   16
#define TQ_  1072          // R + T + S
#define KL_  1072          // M + R + T
#define DH_  64            // D/H
#define NROW 17152         // TQ*B == KL*B
#define K_   512           // inner dim for ALL three GEMMs
#define LQ_  268           // KL/4 (key-quad groups)
#define QSCALE 0.18033688f // 0.125 * log2(e): folded into Q projection

typedef unsigned short u16;
using bf16x8 = __attribute__((ext_vector_type(8))) short;
using f32x4  = __attribute__((ext_vector_type(4))) float;
using u16x4  = __attribute__((ext_vector_type(4))) unsigned short;

__device__ __forceinline__ u16 f2bf(float f) {
    unsigned int u = __builtin_bit_cast(unsigned int, f);
    unsigned int r = u + 0x7fffu + ((u >> 16) & 1u);
    return (u16)(r >> 16);
}

// pack 2 f32 -> 2 bf16 in one u32 (RTNE), T12 recipe
__device__ __forceinline__ unsigned int cvt_pk_bf16(float a, float b) {
    unsigned int r;
    asm("v_cvt_pk_bf16_f32 %0, %1, %2" : "=v"(r) : "v"(a), "v"(b));
    return r;
}

// async global->LDS, 16B per lane; LDS dest = wave-uniform base + lane*16
__device__ __forceinline__ void gload_lds16(const u16* g, u16* l) {
    __builtin_amdgcn_global_load_lds(
        (const __attribute__((address_space(1))) unsigned int*)g,
        (__attribute__((address_space(3))) unsigned int*)l,
        16, 0, 0);
}

// bijective XCD swizzle (m204): hw bid -> logical wgid; same-XCD bids get a
// contiguous logical range so L2-shared operands stay on one XCD.
__device__ __forceinline__ int xcd_swz(int bid, int nwg) {
    const int q = nwg >> 3, r = nwg & 7;
    const int xcd = bid & 7, idx = bid >> 3;
    return (xcd < r ? xcd * (q + 1) : r * (q + 1) + (xcd - r) * q) + idx;
}

// ---------------------------------------------------------------------------
// Stage 1: single gathered buffer xall = [mems | rc | utt | smr] (17408 rows)
//   xkv = xall[0:17152], xq = xall[256:17408]
// ---------------------------------------------------------------------------
__global__ void k_convert4(const float4* __restrict__ utt, const float4* __restrict__ rc,
                           const float4* __restrict__ smr, const float4* __restrict__ mems,
                           const float4* __restrict__ Wq, const float4* __restrict__ Wkv,
                           const float4* __restrict__ Wo,
                           u16x4* __restrict__ xall,
                           u16x4* __restrict__ wq, u16x4* __restrict__ wkv,
                           u16x4* __restrict__ wo)
{
    const int N4 = 17408 * D_ / 4;
    const int MB = M_ * B_ * D_ / 4;
    const int RB = MB + R_ * B_ * D_ / 4;
    const int UB = RB + T_ * B_ * D_ / 4;
    const int W1 = D_ * D_ / 4, W2 = 2 * D_ * D_ / 4;
    for (int i = blockIdx.x * blockDim.x + threadIdx.x; i < N4;
         i += gridDim.x * blockDim.x) {
        float4 v;
        if (i < MB)      v = mems[i];
        else if (i < RB) v = rc[i - MB];
        else if (i < UB) v = utt[i - RB];
        else             v = smr[i - UB];
        xall[i] = (u16x4){f2bf(v.x), f2bf(v.y), f2bf(v.z), f2bf(v.w)};
        if (i < W1) { v = Wq[i];  wq[i]  = (u16x4){f2bf(v.x), f2bf(v.y), f2bf(v.z), f2bf(v.w)}; }
        if (i < W2) { v = Wkv[i]; wkv[i] = (u16x4){f2bf(v.x), f2bf(v.y), f2bf(v.z), f2bf(v.w)}; }
        if (i < W1) { v = Wo[i];  wo[i]  = (u16x4){f2bf(v.x), f2bf(v.y), f2bf(v.z), f2bf(v.w)}; }
    }
}

// ---------------------------------------------------------------------------
// m97-structure GEMM core: 256 thr / 4 waves, 128x128 tile, BK=64, SINGLE
// 32 KB LDS buffer, 2-barrier k-loop. 5 blocks/CU (LDS-limited) -> cross-
// block implicit overlap hides load latency (m114/m97: the proven mechanism
// at 3-5 blocks/CU; beats 1-block explicit pipelining at this shape).
// Wave w owns rows [w*32, w*32+32) x all 128 cols: acc 2(M) x 8(N).
// Rows are 64 u16 = 8 chunks of 8; chunk c of row r at slot c^(r&7)
// (verified 0 bank conflicts).
//   TOR=false: acc[mi*8+ni] = mfma(aF,bF): D rows = X-rows (quad*4+r)
//   TOR=true : acc[ni*2+mi] = mfma(bF,aF): D rows = W-cols (quad*4+r)
// ---------------------------------------------------------------------------
template<bool TOR>
__device__ __forceinline__ void core128(const u16* __restrict__ Ab,
                                        const u16* __restrict__ Wb,
                                        f32x4* acc)
{
    __shared__ __align__(16) u16 As[128 * 64];
    __shared__ __align__(16) u16 Bs[128 * 64];

    const int tid  = threadIdx.x;
    const int w    = tid >> 6, lane = tid & 63;
    const int col  = lane & 15, quad = lane >> 4;
    const int sr   = tid >> 3;                 // 0..31 staging row in round
    const int sc   = (tid & 7) ^ (sr & 7);     // pre-swizzled source chunk
    const u16* gA  = Ab + (size_t)sr * K_ + sc * 8;
    const u16* gB  = Wb + (size_t)sr * K_ + sc * 8;

#pragma unroll
    for (int i = 0; i < 16; i++) acc[i] = (f32x4){0.f, 0.f, 0.f, 0.f};

    for (int kt = 0; kt < 8; ++kt) {
        __syncthreads();                       // readers done with buffer
#pragma unroll
        for (int i = 0; i < 4; i++)            // A: 128 rows, 4 rounds of 32
            gload_lds16(gA + (size_t)(i * 32) * K_ + kt * 64,
                        &As[(i * 32 + w * 8) * 64]);
#pragma unroll
        for (int i = 0; i < 4; i++)            // B: 128 rows, 4 rounds of 32
            gload_lds16(gB + (size_t)(i * 32) * K_ + kt * 64,
                        &Bs[(i * 32 + w * 8) * 64]);
        __syncthreads();                       // tile visible (vmcnt drain)
#pragma unroll
        for (int kh = 0; kh < 2; ++kh) {
            bf16x8 aF[2], bF[8];
#pragma unroll
            for (int mi = 0; mi < 2; mi++)
                aF[mi] = *(const bf16x8*)&As[(w * 32 + mi * 16 + col) * 64
                             + (((kh * 4 + quad) ^ (col & 7)) * 8)];
#pragma unroll
            for (int ni = 0; ni < 8; ni++)
                bF[ni] = *(const bf16x8*)&Bs[(ni * 16 + col) * 64
                             + (((kh * 4 + quad) ^ (col & 7)) * 8)];
            if (TOR) {
#pragma unroll
                for (int ni = 0; ni < 8; ni++)
#pragma unroll
                    for (int mi = 0; mi < 2; mi++)
                        acc[ni * 2 + mi] = __builtin_amdgcn_mfma_f32_16x16x32_bf16(
                            bF[ni], aF[mi], acc[ni * 2 + mi], 0, 0, 0);
            } else {
#pragma unroll
                for (int mi = 0; mi < 2; mi++)
#pragma unroll
                    for (int ni = 0; ni < 8; ni++)
                        acc[mi * 8 + ni] = __builtin_amdgcn_mfma_f32_16x16x32_bf16(
                            aF[mi], bF[ni], acc[mi * 8 + ni], 0, 0, 0);
            }
        }
    }
}

// ---------------------------------------------------------------------------
// Merged Q+KV projection. Logical wgid (XCD-swizzled, tn-minor): tn 0..3 ->
// Q, 4..7 -> K, 8..11 -> V (128-col tiles); tm 0..133 (128-row tiles).
// Q/K: TOR core, 8B coalesced stores; V: N core, transpose-pack to
// vt[b][l/4][f][4] (two l-slots per wave -> 4B stores).
// ---------------------------------------------------------------------------
__global__ __launch_bounds__(256, 4)
void k_gemm_qkv9(const u16* __restrict__ xall,
                 const u16* __restrict__ wqp, const u16* __restrict__ wkvp,
                 const float* __restrict__ bq, const float* __restrict__ bkv,
                 u16* __restrict__ qb, u16* __restrict__ kb, u16* __restrict__ vt)
{
    const int wgid = xcd_swz(blockIdx.x, 134 * 12);
    const int tn = wgid % 12, tm = wgid / 12;
    const int typ = tn >> 2, sub = tn & 3;    // 0=Q, 1=K, 2=V
    const u16* Ab = (typ == 0 ? xall + (size_t)256 * K_ : xall)
                    + (size_t)tm * 128 * K_;
    const u16* Wb = (typ == 0 ? wqp : wkvp + (typ == 2 ? (size_t)512 * K_ : 0))
                    + (size_t)sub * 128 * K_;

    const int tid = threadIdx.x;
    const int w = tid >> 6, lane = tid & 63;
    const int col = lane & 15, quad = lane >> 4;

    f32x4 acc[16];
    if (typ == 2) {
        core128<false>(Ab, Wb, acc);
        // V -> vt[b][l/4][f][4]; l = tm*8 + w*2 + mi; b = quad*4+r
        const int lq = tm * 2 + (w >> 1);
        const int so = (w & 1) * 2;           // l%4 = so + mi
#pragma unroll
        for (int ni = 0; ni < 8; ni++) {
            const int f = sub * 128 + ni * 16 + col;
            const float bs = bkv[512 + f];
#pragma unroll
            for (int r = 0; r < 4; r++) {
                const int bb = quad * 4 + r;
                unsigned int pk = cvt_pk_bf16(acc[0 * 8 + ni][r] + bs,
                                              acc[1 * 8 + ni][r] + bs);
                *(unsigned int*)&vt[(((size_t)bb * LQ_ + lq) * 512 + f) * 4 + so] = pk;
            }
        }
    } else {
        core128<true>(Ab, Wb, acc);
        const float* bias = (typ == 0) ? bq : bkv;
        u16* outp = (typ == 0) ? qb : kb;
        const float qs = (typ == 0) ? QSCALE : 1.0f;
#pragma unroll
        for (int ni = 0; ni < 8; ni++) {
            const int gc0 = sub * 128 + ni * 16 + quad * 4;
            const float4 bs4 = *(const float4*)&bias[gc0];
#pragma unroll
            for (int mi = 0; mi < 2; mi++) {
                const int mrow = tm * 128 + w * 32 + mi * 16 + col;
                f32x4 a = acc[ni * 2 + mi];
                uint2 pk;
                pk.x = cvt_pk_bf16((a[0] + bs4.x) * qs, (a[1] + bs4.y) * qs);
                pk.y = cvt_pk_bf16((a[2] + bs4.z) * qs, (a[3] + bs4.w) * qs);
                *(uint2*)&outp[(size_t)mrow * 512 + gc0] = pk;
            }
        }
    }
}

// ---------------------------------------------------------------------------
// Output projection + clip/slice epilogue (fp32 out), TOR core, float4 stores.
// Logical wgid: tn 0..3 (128-col tiles), tm 0..133 (128-row tiles).
// ---------------------------------------------------------------------------
__global__ __launch_bounds__(256, 4)
void k_gemm_o9(const u16* __restrict__ A, const u16* __restrict__ W,
               const float* __restrict__ bias, float* __restrict__ Co)
{
    const int wgid = xcd_swz(blockIdx.x, 134 * 4);
    const int tn = wgid % 4, tm = wgid / 4;
    const u16* Ab = A + (size_t)tm * 128 * K_;
    const u16* Wb = W + (size_t)tn * 128 * K_;

    const int tid = threadIdx.x;
    const int w = tid >> 6, lane = tid & 63;
    const int col = lane & 15, quad = lane >> 4;

    f32x4 acc[16];
    core128<true>(Ab, Wb, acc);

#pragma unroll
    for (int ni = 0; ni < 8; ni++) {
        const int gc0 = tn * 128 + ni * 16 + quad * 4;
        const float4 bs4 = *(const float4*)&bias[gc0];
#pragma unroll
        for (int mi = 0; mi < 2; mi++) {
            const int l = tm * 8 + w * 2 + mi;
            if (l == TQ_ - 1) continue;
            const int mrow = tm * 128 + w * 32 + mi * 16 + col;
            f32x4 a = acc[ni * 2 + mi];
            float4 v = {a[0] + bs4.x, a[1] + bs4.y, a[2] + bs4.z, a[3] + bs4.w};
            if (l >= TQ_ - S_) {
                v.x = fminf(10.0f, fmaxf(-10.0f, v.x));
                v.y = fminf(10.0f, fmaxf(-10.0f, v.y));
                v.z = fminf(10.0f, fmaxf(-10.0f, v.z));
                v.w = fminf(10.0f, fmaxf(-10.0f, v.w));
            }
            *(float4*)&Co[(size_t)mrow * 512 + gc0] = v;
        }
    }
}

// ---------------------------------------------------------------------------
// Flash attention v6: no online max (scores bounded, exp2 directly).
// PV operands swapped: o = mfma(V^T-frag, P-frag) -> d-dim lane-consecutive,
// li normalizer lane-local. cvt_pk packing throughout.
// ---------------------------------------------------------------------------
__global__ __launch_bounds__(256, 2)
void k_attn5(const u16* __restrict__ qbuf, const u16* __restrict__ kb,
             const u16* __restrict__ vt, const int* __restrict__ lenp,
             u16* __restrict__ attnb)
{
    __shared__ __align__(16) u16 Ks[2][64 * 64];
    __shared__ __align__(16) u16 Vs[2][64 * 64];
    __shared__ __align__(16) u16 Ps[4][16 * 64];

    const int blk  = blockIdx.x;
    const int qblk = 16 - (blk >> 7);       // heavy (qblk=16) first
    const int bh   = blk & 127;             // blk%8 == h -> head pinned to XCD
    const int b = bh >> 3, h = bh & 7;
    const int tid = threadIdx.x;
    const int w = tid >> 6, lane = tid & 63;
    const int col = lane & 15, quad = lane >> 4;

    int stride = (lenp[1] == 0) ? 2 : 1;
    int maxlen = 0;
    for (int i = 0; i < B_; i++) maxlen = max(maxlen, lenp[i * stride]);
    const int klen = lenp[b * stride] + M_ + (TQ_ - maxlen - S_);

    const int q0 = qblk * 64;
    const int qw = q0 + w * 16;
    const int q  = qw + col;

    int qrow = min(q, TQ_ - 1);
    const u16* qp = qbuf + ((size_t)qrow * B_ + b) * D_ + h * DH_ + quad * 8;
    bf16x8 bq0 = *(const bf16x8*)(qp);
    bf16x8 bq1 = *(const bf16x8*)(qp + 32);

    const int s0 = tid, s1 = tid + 256;
    const u16* kbase = kb + (size_t)b * 512 + h * DH_;
    size_t kof0 = (size_t)(s0 >> 3) * 8192 + (size_t)(((s0 & 7) ^ ((s0 >> 3) & 7)) * 8);
    size_t kof1 = (size_t)(s1 >> 3) * 8192 + (size_t)(((s1 & 7) ^ ((s1 >> 3) & 7)) * 8);
    const u16* vbase = vt + ((size_t)b * LQ_ * 512 + (size_t)h * DH_) * 4;
    auto vchunk = [](int s) -> size_t {
        int fp = s >> 4;
        int lq = (s & 15) ^ (fp & 15);
        return (size_t)lq * 2048 + (size_t)fp * 8;
    };
    const size_t vof0 = vchunk(s0), vof1 = vchunk(s1);

    float li = 0.f;                         // per-lane partial sum of p (q = col)
    f32x4 o[4];
#pragma unroll
    for (int g = 0; g < 4; g++) o[g] = (f32x4){0.f, 0.f, 0.f, 0.f};

    const int nk = min(q0 + 64 + M_, klen);
    const int numkt = (nk + 63) >> 6;
    u16* pw = &Ps[w][0];

    gload_lds16(kbase + kof0, &Ks[0][(size_t)w * 512]);
    gload_lds16(kbase + kof1, &Ks[0][2048 + (size_t)w * 512]);
    gload_lds16(vbase + vof0, &Vs[0][(size_t)w * 512]);
    gload_lds16(vbase + vof1, &Vs[0][2048 + (size_t)w * 512]);

    for (int kt = 0; kt < numkt; kt++) {
        const int kn0 = kt * 64;
        const int cur = kt & 1;
        __syncthreads();
        if (kt + 1 < numkt) {
            const size_t kstep = (size_t)(kn0 + 64) * 8192;
            const size_t vstep = (size_t)(kt + 1) * 32768;
            gload_lds16(kbase + kstep + kof0, &Ks[cur ^ 1][(size_t)w * 512]);
            gload_lds16(kbase + kstep + kof1, &Ks[cur ^ 1][2048 + (size_t)w * 512]);
            gload_lds16(vbase + vstep + vof0, &Vs[cur ^ 1][(size_t)w * 512]);
            gload_lds16(vbase + vstep + vof1, &Vs[cur ^ 1][2048 + (size_t)w * 512]);
        }

        // QK^T (Q pre-scaled into exp2 domain): sc[g][r] = S[kn0+g*16+quad*4+r][q=col]
        f32x4 sc[4];
        __builtin_amdgcn_s_setprio(1);
#pragma unroll
        for (int g = 0; g < 4; g++) {
            int key = g * 16 + col;
            bf16x8 a0 = *(const bf16x8*)&Ks[cur][key * 64 + ((quad ^ (key & 7)) * 8)];
            bf16x8 a1 = *(const bf16x8*)&Ks[cur][key * 64 + (((4 + quad) ^ (key & 7)) * 8)];
            f32x4 z = {0.f, 0.f, 0.f, 0.f};
            z = __builtin_amdgcn_mfma_f32_16x16x32_bf16(a0, bq0, z, 0, 0, 0);
            z = __builtin_amdgcn_mfma_f32_16x16x32_bf16(a1, bq1, z, 0, 0, 0);
            sc[g] = z;
        }
        __builtin_amdgcn_s_setprio(0);

        // boundary-only masking
        const bool needmask = (kn0 + 63 > qw + M_) || (kn0 + 63 >= klen);
        if (needmask) {
#pragma unroll
            for (int g = 0; g < 4; g++)
#pragma unroll
                for (int r = 0; r < 4; r++) {
                    int key = kn0 + g * 16 + quad * 4 + r;
                    bool valid = (key <= q + M_) && (key < klen);
                    sc[g][r] = valid ? sc[g][r] : -1e8f;
                }
        }

        // p = exp2(s): local sum, cvt_pk pack to LDS (P[q=col][key])
#pragma unroll
        for (int g = 0; g < 4; g++) {
            float pr[4];
#pragma unroll
            for (int r = 0; r < 4; r++) {
                pr[r] = __builtin_amdgcn_exp2f(sc[g][r]);
                li += pr[r];
            }
            uint2 pk;
            pk.x = cvt_pk_bf16(pr[0], pr[1]);
            pk.y = cvt_pk_bf16(pr[2], pr[3]);
            int kc = g * 2 + (quad >> 1);
            *(uint2*)&pw[col * 64 + ((kc ^ (col & 7)) * 8) + (quad & 1) * 4] = pk;
        }

        // PV swapped: A = V^T-frag (m=d), B = P-frag (n=q); D[d][q]
        bf16x8 ap0 = *(const bf16x8*)&pw[col * 64 + ((quad ^ (col & 7)) * 8)];
        bf16x8 ap1 = *(const bf16x8*)&pw[col * 64 + (((4 + quad) ^ (col & 7)) * 8)];
        __builtin_amdgcn_s_setprio(1);
#pragma unroll
        for (int g = 0; g < 4; g++) {
            int d = g * 16 + col;
            int fp = d >> 1, fo = (d & 1) * 4;
            bf16x8 bv[2];
#pragma unroll
            for (int hh = 0; hh < 2; hh++) {
                int lqA = hh * 8 + quad * 2;
                int posA = fp * 16 + (lqA ^ (fp & 15));
                int posB = fp * 16 + ((lqA + 1) ^ (fp & 15));
                u16x4 loA = *(const u16x4*)&Vs[cur][posA * 8 + fo];
                u16x4 loB = *(const u16x4*)&Vs[cur][posB * 8 + fo];
                bf16x8 t;
                t[0] = loA[0]; t[1] = loA[1]; t[2] = loA[2]; t[3] = loA[3];
                t[4] = loB[0]; t[5] = loB[1]; t[6] = loB[2]; t[7] = loB[3];
                bv[hh] = t;
            }
            o[g] = __builtin_amdgcn_mfma_f32_16x16x32_bf16(bv[0], ap0, o[g], 0, 0, 0);
            o[g] = __builtin_amdgcn_mfma_f32_16x16x32_bf16(bv[1], ap1, o[g], 0, 0, 0);
        }
        __builtin_amdgcn_s_setprio(0);
    }

    // l reduction across quads; q = col is lane-local so inv applies directly
    li += __shfl_xor(li, 16);
    li += __shfl_xor(li, 32);
    const float inv = 1.0f / li;
    const int qo = qw + col;
    if (qw + 16 <= TQ_) {
#pragma unroll
        for (int g = 0; g < 4; g++) {
            uint2 pk;
            pk.x = cvt_pk_bf16(o[g][0] * inv, o[g][1] * inv);
            pk.y = cvt_pk_bf16(o[g][2] * inv, o[g][3] * inv);
            *(uint2*)&attnb[((size_t)qo * B_ + b) * D_ + h * DH_ + g * 16 + quad * 4] = pk;
        }
    }
}

// ---------------------------------------------------------------------------
extern "C" void kernel_launch(void* const* d_in, const int* in_sizes, int n_in,
                              void* d_out, int out_size, void* d_ws, size_t ws_size,
                              hipStream_t stream)
{
    const float* utt  = (const float*)d_in[0];
    const int*   len  = (const int*)  d_in[1];
    const float* rc   = (const float*)d_in[2];
    const float* smr  = (const float*)d_in[3];
    const float* mems = (const float*)d_in[4];
    const float* Wq   = (const float*)d_in[6];
    const float* bq   = (const float*)d_in[7];
    const float* Wkv  = (const float*)d_in[8];
    const float* bkv  = (const float*)d_in[9];
    const float* Wo   = (const float*)d_in[10];
    const float* bo   = (const float*)d_in[11];

    char* ws = (char*)d_ws;
    size_t off = 0;
    auto alloc = [&](size_t bytes) -> void* {
        void* p = ws + off;
        off += (bytes + 255) & ~(size_t)255;
        return p;
    };
    u16* xall = (u16*)alloc((size_t)17408 * D_ * 2);
    u16* wq   = (u16*)alloc((size_t)D_ * D_ * 2);
    u16* wkv  = (u16*)alloc((size_t)2 * D_ * D_ * 2);
    u16* wo   = (u16*)alloc((size_t)D_ * D_ * 2);
    u16* qb   = (u16*)alloc((size_t)NROW * D_ * 2);
    u16* kb   = (u16*)alloc((size_t)NROW * D_ * 2);
    u16* vt   = (u16*)alloc((size_t)B_ * LQ_ * 512 * 4 * 2 + 65536);
    u16* attnb = xall;  // xall dead after QKV-GEMM

    k_convert4<<<2048, 256, 0, stream>>>((const float4*)utt, (const float4*)rc,
                                         (const float4*)smr, (const float4*)mems,
                                         (const float4*)Wq, (const float4*)Wkv,
                                         (const float4*)Wo,
                                         (u16x4*)xall,
                                         (u16x4*)wq, (u16x4*)wkv, (u16x4*)wo);
    k_gemm_qkv9<<<134 * 12, 256, 0, stream>>>(xall, wq, wkv, bq, bkv, qb, kb, vt);
    k_attn5<<<17 * 128, 256, 0, stream>>>(qb, kb, vt, len, attnb);
    k_gemm_o9<<<134 * 4, 256, 0, stream>>>(attnb, wo, bo, (float*)d_out);
}

// Round 8
// 210.026 us; speedup vs baseline: 1.0552x; 1.0279x over previous
//
#include <hip/hip_runtime.h>

// Problem constants (Emformer layer)
#define T_   1024
#define B_   16
#define D_   512
#define H_   8
#define R_   32
#define S_   16
#define M_   16
#define TQ_  1072          // R + T + S
#define KL_  1072          // M + R + T
#define DH_  64            // D/H
#define NROW 17152         // TQ*B == KL*B
#define K_   512           // inner dim for ALL three GEMMs
#define LQ_  268           // KL/4 (key-quad groups)
#define QSCALE 0.18033688f // 0.125 * log2(e): folded into Q projection

typedef unsigned short u16;
using bf16x8 = __attribute__((ext_vector_type(8))) short;
using f32x4  = __attribute__((ext_vector_type(4))) float;
using u16x4  = __attribute__((ext_vector_type(4))) unsigned short;

__device__ __forceinline__ u16 f2bf(float f) {
    unsigned int u = __builtin_bit_cast(unsigned int, f);
    unsigned int r = u + 0x7fffu + ((u >> 16) & 1u);
    return (u16)(r >> 16);
}

// pack 2 f32 -> 2 bf16 in one u32 (RTNE), T12 recipe
__device__ __forceinline__ unsigned int cvt_pk_bf16(float a, float b) {
    unsigned int r;
    asm("v_cvt_pk_bf16_f32 %0, %1, %2" : "=v"(r) : "v"(a), "v"(b));
    return r;
}

// async global->LDS, 16B per lane; LDS dest = wave-uniform base + lane*16
__device__ __forceinline__ void gload_lds16(const u16* g, u16* l) {
    __builtin_amdgcn_global_load_lds(
        (const __attribute__((address_space(1))) unsigned int*)g,
        (__attribute__((address_space(3))) unsigned int*)l,
        16, 0, 0);
}

// bijective XCD swizzle (m204): hw bid -> logical wgid; same-XCD bids get a
// contiguous logical range so L2-shared operands stay on one XCD.
__device__ __forceinline__ int xcd_swz(int bid, int nwg) {
    const int q = nwg >> 3, r = nwg & 7;
    const int xcd = bid & 7, idx = bid >> 3;
    return (xcd < r ? xcd * (q + 1) : r * (q + 1) + (xcd - r) * q) + idx;
}

// ---------------------------------------------------------------------------
// Stage 1: single gathered buffer xall = [mems | rc | utt | smr] (17408 rows)
//   xkv = xall[0:17152], xq = xall[256:17408]
// ---------------------------------------------------------------------------
__global__ void k_convert4(const float4* __restrict__ utt, const float4* __restrict__ rc,
                           const float4* __restrict__ smr, const float4* __restrict__ mems,
                           const float4* __restrict__ Wq, const float4* __restrict__ Wkv,
                           const float4* __restrict__ Wo,
                           u16x4* __restrict__ xall,
                           u16x4* __restrict__ wq, u16x4* __restrict__ wkv,
                           u16x4* __restrict__ wo)
{
    const int N4 = 17408 * D_ / 4;
    const int MB = M_ * B_ * D_ / 4;
    const int RB = MB + R_ * B_ * D_ / 4;
    const int UB = RB + T_ * B_ * D_ / 4;
    const int W1 = D_ * D_ / 4, W2 = 2 * D_ * D_ / 4;
    for (int i = blockIdx.x * blockDim.x + threadIdx.x; i < N4;
         i += gridDim.x * blockDim.x) {
        float4 v;
        if (i < MB)      v = mems[i];
        else if (i < RB) v = rc[i - MB];
        else if (i < UB) v = utt[i - RB];
        else             v = smr[i - UB];
        xall[i] = (u16x4){f2bf(v.x), f2bf(v.y), f2bf(v.z), f2bf(v.w)};
        if (i < W1) { v = Wq[i];  wq[i]  = (u16x4){f2bf(v.x), f2bf(v.y), f2bf(v.z), f2bf(v.w)}; }
        if (i < W2) { v = Wkv[i]; wkv[i] = (u16x4){f2bf(v.x), f2bf(v.y), f2bf(v.z), f2bf(v.w)}; }
        if (i < W1) { v = Wo[i];  wo[i]  = (u16x4){f2bf(v.x), f2bf(v.y), f2bf(v.z), f2bf(v.w)}; }
    }
}

// ---------------------------------------------------------------------------
// m97-structure GEMM core: 256 thr / 4 waves, 128x128 tile, BK=64, SINGLE
// 32 KB LDS buffer (PASSED IN -- declared once per kernel so both template
// instantiations share one allocation; r6 bug: per-instantiation static
// __shared__ doubled LDS to 64 KB and halved occupancy), 2-barrier k-loop.
// 5 blocks/CU -> cross-block implicit overlap hides load latency (m114/m97).
// Wave w owns rows [w*32, w*32+32) x all 128 cols: acc 2(M) x 8(N).
// Rows are 64 u16 = 8 chunks of 8; chunk c of row r at slot c^(r&7)
// (verified 0 bank conflicts).
//   TOR=false: acc[mi*8+ni] = mfma(aF,bF): D rows = X-rows (quad*4+r)
//   TOR=true : acc[ni*2+mi] = mfma(bF,aF): D rows = W-cols (quad*4+r)
// ---------------------------------------------------------------------------
template<bool TOR>
__device__ __forceinline__ void core128(const u16* __restrict__ Ab,
                                        const u16* __restrict__ Wb,
                                        u16* As, u16* Bs, f32x4* acc)
{
    const int tid  = threadIdx.x;
    const int w    = tid >> 6, lane = tid & 63;
    const int col  = lane & 15, quad = lane >> 4;
    const int sr   = tid >> 3;                 // 0..31 staging row in round
    const int sc   = (tid & 7) ^ (sr & 7);     // pre-swizzled source chunk
    const u16* gA  = Ab + (size_t)sr * K_ + sc * 8;
    const u16* gB  = Wb + (size_t)sr * K_ + sc * 8;

#pragma unroll
    for (int i = 0; i < 16; i++) acc[i] = (f32x4){0.f, 0.f, 0.f, 0.f};

    for (int kt = 0; kt < 8; ++kt) {
        __syncthreads();                       // readers done with buffer
#pragma unroll
        for (int i = 0; i < 4; i++)            // A: 128 rows, 4 rounds of 32
            gload_lds16(gA + (size_t)(i * 32) * K_ + kt * 64,
                        &As[(i * 32 + w * 8) * 64]);
#pragma unroll
        for (int i = 0; i < 4; i++)            // B: 128 rows, 4 rounds of 32
            gload_lds16(gB + (size_t)(i * 32) * K_ + kt * 64,
                        &Bs[(i * 32 + w * 8) * 64]);
        __syncthreads();                       // tile visible (vmcnt drain)
#pragma unroll
        for (int kh = 0; kh < 2; ++kh) {
            bf16x8 aF[2], bF[8];
#pragma unroll
            for (int mi = 0; mi < 2; mi++)
                aF[mi] = *(const bf16x8*)&As[(w * 32 + mi * 16 + col) * 64
                             + (((kh * 4 + quad) ^ (col & 7)) * 8)];
#pragma unroll
            for (int ni = 0; ni < 8; ni++)
                bF[ni] = *(const bf16x8*)&Bs[(ni * 16 + col) * 64
                             + (((kh * 4 + quad) ^ (col & 7)) * 8)];
            if (TOR) {
#pragma unroll
                for (int ni = 0; ni < 8; ni++)
#pragma unroll
                    for (int mi = 0; mi < 2; mi++)
                        acc[ni * 2 + mi] = __builtin_amdgcn_mfma_f32_16x16x32_bf16(
                            bF[ni], aF[mi], acc[ni * 2 + mi], 0, 0, 0);
            } else {
#pragma unroll
                for (int mi = 0; mi < 2; mi++)
#pragma unroll
                    for (int ni = 0; ni < 8; ni++)
                        acc[mi * 8 + ni] = __builtin_amdgcn_mfma_f32_16x16x32_bf16(
                            aF[mi], bF[ni], acc[mi * 8 + ni], 0, 0, 0);
            }
        }
    }
}

// ---------------------------------------------------------------------------
// Merged Q+KV projection. Logical wgid (XCD-swizzled, tn-minor): tn 0..3 ->
// Q, 4..7 -> K, 8..11 -> V (128-col tiles); tm 0..133 (128-row tiles).
// Q/K: TOR core, 8B coalesced stores; V: N core, transpose-pack to
// vt[b][l/4][f][4] (two l-slots per wave -> 4B stores).
// ---------------------------------------------------------------------------
__global__ __launch_bounds__(256, 4)
void k_gemm_qkv9(const u16* __restrict__ xall,
                 const u16* __restrict__ wqp, const u16* __restrict__ wkvp,
                 const float* __restrict__ bq, const float* __restrict__ bkv,
                 u16* __restrict__ qb, u16* __restrict__ kb, u16* __restrict__ vt)
{
    __shared__ __align__(16) u16 As[128 * 64];
    __shared__ __align__(16) u16 Bs[128 * 64];

    const int wgid = xcd_swz(blockIdx.x, 134 * 12);
    const int tn = wgid % 12, tm = wgid / 12;
    const int typ = tn >> 2, sub = tn & 3;    // 0=Q, 1=K, 2=V
    const u16* Ab = (typ == 0 ? xall + (size_t)256 * K_ : xall)
                    + (size_t)tm * 128 * K_;
    const u16* Wb = (typ == 0 ? wqp : wkvp + (typ == 2 ? (size_t)512 * K_ : 0))
                    + (size_t)sub * 128 * K_;

    const int tid = threadIdx.x;
    const int w = tid >> 6, lane = tid & 63;
    const int col = lane & 15, quad = lane >> 4;

    f32x4 acc[16];
    if (typ == 2) {
        core128<false>(Ab, Wb, As, Bs, acc);
        // V -> vt[b][l/4][f][4]; l = tm*8 + w*2 + mi; b = quad*4+r
        const int lq = tm * 2 + (w >> 1);
        const int so = (w & 1) * 2;           // l%4 = so + mi
#pragma unroll
        for (int ni = 0; ni < 8; ni++) {
            const int f = sub * 128 + ni * 16 + col;
            const float bs = bkv[512 + f];
#pragma unroll
            for (int r = 0; r < 4; r++) {
                const int bb = quad * 4 + r;
                unsigned int pk = cvt_pk_bf16(acc[0 * 8 + ni][r] + bs,
                                              acc[1 * 8 + ni][r] + bs);
                *(unsigned int*)&vt[(((size_t)bb * LQ_ + lq) * 512 + f) * 4 + so] = pk;
            }
        }
    } else {
        core128<true>(Ab, Wb, As, Bs, acc);
        const float* bias = (typ == 0) ? bq : bkv;
        u16* outp = (typ == 0) ? qb : kb;
        const float qs = (typ == 0) ? QSCALE : 1.0f;
#pragma unroll
        for (int ni = 0; ni < 8; ni++) {
            const int gc0 = sub * 128 + ni * 16 + quad * 4;
            const float4 bs4 = *(const float4*)&bias[gc0];
#pragma unroll
            for (int mi = 0; mi < 2; mi++) {
                const int mrow = tm * 128 + w * 32 + mi * 16 + col;
                f32x4 a = acc[ni * 2 + mi];
                uint2 pk;
                pk.x = cvt_pk_bf16((a[0] + bs4.x) * qs, (a[1] + bs4.y) * qs);
                pk.y = cvt_pk_bf16((a[2] + bs4.z) * qs, (a[3] + bs4.w) * qs);
                *(uint2*)&outp[(size_t)mrow * 512 + gc0] = pk;
            }
        }
    }
}

// ---------------------------------------------------------------------------
// Output projection + clip/slice epilogue (fp32 out), TOR core, float4 stores.
// Logical wgid: tn 0..3 (128-col tiles), tm 0..133 (128-row tiles).
// ---------------------------------------------------------------------------
__global__ __launch_bounds__(256, 4)
void k_gemm_o9(const u16* __restrict__ A, const u16* __restrict__ W,
               const float* __restrict__ bias, float* __restrict__ Co)
{
    __shared__ __align__(16) u16 As[128 * 64];
    __shared__ __align__(16) u16 Bs[128 * 64];

    const int wgid = xcd_swz(blockIdx.x, 134 * 4);
    const int tn = wgid % 4, tm = wgid / 4;
    const u16* Ab = A + (size_t)tm * 128 * K_;
    const u16* Wb = W + (size_t)tn * 128 * K_;

    const int tid = threadIdx.x;
    const int w = tid >> 6, lane = tid & 63;
    const int col = lane & 15, quad = lane >> 4;

    f32x4 acc[16];
    core128<true>(Ab, Wb, As, Bs, acc);

#pragma unroll
    for (int ni = 0; ni < 8; ni++) {
        const int gc0 = tn * 128 + ni * 16 + quad * 4;
        const float4 bs4 = *(const float4*)&bias[gc0];
#pragma unroll
        for (int mi = 0; mi < 2; mi++) {
            const int l = tm * 8 + w * 2 + mi;
            if (l == TQ_ - 1) continue;
            const int mrow = tm * 128 + w * 32 + mi * 16 + col;
            f32x4 a = acc[ni * 2 + mi];
            float4 v = {a[0] + bs4.x, a[1] + bs4.y, a[2] + bs4.z, a[3] + bs4.w};
            if (l >= TQ_ - S_) {
                v.x = fminf(10.0f, fmaxf(-10.0f, v.x));
                v.y = fminf(10.0f, fmaxf(-10.0f, v.y));
                v.z = fminf(10.0f, fmaxf(-10.0f, v.z));
                v.w = fminf(10.0f, fmaxf(-10.0f, v.w));
            }
            *(float4*)&Co[(size_t)mrow * 512 + gc0] = v;
        }
    }
}

// ---------------------------------------------------------------------------
// Flash attention v6: no online max (scores bounded, exp2 directly).
// PV operands swapped: o = mfma(V^T-frag, P-frag) -> d-dim lane-consecutive,
// li normalizer lane-local. cvt_pk packing throughout.
// ---------------------------------------------------------------------------
__global__ __launch_bounds__(256, 2)
void k_attn5(const u16* __restrict__ qbuf, const u16* __restrict__ kb,
             const u16* __restrict__ vt, const int* __restrict__ lenp,
             u16* __restrict__ attnb)
{
    __shared__ __align__(16) u16 Ks[2][64 * 64];
    __shared__ __align__(16) u16 Vs[2][64 * 64];
    __shared__ __align__(16) u16 Ps[4][16 * 64];

    const int blk  = blockIdx.x;
    const int qblk = 16 - (blk >> 7);       // heavy (qblk=16) first
    const int bh   = blk & 127;             // blk%8 == h -> head pinned to XCD
    const int b = bh >> 3, h = bh & 7;
    const int tid = threadIdx.x;
    const int w = tid >> 6, lane = tid & 63;
    const int col = lane & 15, quad = lane >> 4;

    int stride = (lenp[1] == 0) ? 2 : 1;
    int maxlen = 0;
    for (int i = 0; i < B_; i++) maxlen = max(maxlen, lenp[i * stride]);
    const int klen = lenp[b * stride] + M_ + (TQ_ - maxlen - S_);

    const int q0 = qblk * 64;
    const int qw = q0 + w * 16;
    const int q  = qw + col;

    int qrow = min(q, TQ_ - 1);
    const u16* qp = qbuf + ((size_t)qrow * B_ + b) * D_ + h * DH_ + quad * 8;
    bf16x8 bq0 = *(const bf16x8*)(qp);
    bf16x8 bq1 = *(const bf16x8*)(qp + 32);

    const int s0 = tid, s1 = tid + 256;
    const u16* kbase = kb + (size_t)b * 512 + h * DH_;
    size_t kof0 = (size_t)(s0 >> 3) * 8192 + (size_t)(((s0 & 7) ^ ((s0 >> 3) & 7)) * 8);
    size_t kof1 = (size_t)(s1 >> 3) * 8192 + (size_t)(((s1 & 7) ^ ((s1 >> 3) & 7)) * 8);
    const u16* vbase = vt + ((size_t)b * LQ_ * 512 + (size_t)h * DH_) * 4;
    auto vchunk = [](int s) -> size_t {
        int fp = s >> 4;
        int lq = (s & 15) ^ (fp & 15);
        return (size_t)lq * 2048 + (size_t)fp * 8;
    };
    const size_t vof0 = vchunk(s0), vof1 = vchunk(s1);

    float li = 0.f;                         // per-lane partial sum of p (q = col)
    f32x4 o[4];
#pragma unroll
    for (int g = 0; g < 4; g++) o[g] = (f32x4){0.f, 0.f, 0.f, 0.f};

    const int nk = min(q0 + 64 + M_, klen);
    const int numkt = (nk + 63) >> 6;
    u16* pw = &Ps[w][0];

    gload_lds16(kbase + kof0, &Ks[0][(size_t)w * 512]);
    gload_lds16(kbase + kof1, &Ks[0][2048 + (size_t)w * 512]);
    gload_lds16(vbase + vof0, &Vs[0][(size_t)w * 512]);
    gload_lds16(vbase + vof1, &Vs[0][2048 + (size_t)w * 512]);

    for (int kt = 0; kt < numkt; kt++) {
        const int kn0 = kt * 64;
        const int cur = kt & 1;
        __syncthreads();
        if (kt + 1 < numkt) {
            const size_t kstep = (size_t)(kn0 + 64) * 8192;
            const size_t vstep = (size_t)(kt + 1) * 32768;
            gload_lds16(kbase + kstep + kof0, &Ks[cur ^ 1][(size_t)w * 512]);
            gload_lds16(kbase + kstep + kof1, &Ks[cur ^ 1][2048 + (size_t)w * 512]);
            gload_lds16(vbase + vstep + vof0, &Vs[cur ^ 1][(size_t)w * 512]);
            gload_lds16(vbase + vstep + vof1, &Vs[cur ^ 1][2048 + (size_t)w * 512]);
        }

        // QK^T (Q pre-scaled into exp2 domain): sc[g][r] = S[kn0+g*16+quad*4+r][q=col]
        f32x4 sc[4];
        __builtin_amdgcn_s_setprio(1);
#pragma unroll
        for (int g = 0; g < 4; g++) {
            int key = g * 16 + col;
            bf16x8 a0 = *(const bf16x8*)&Ks[cur][key * 64 + ((quad ^ (key & 7)) * 8)];
            bf16x8 a1 = *(const bf16x8*)&Ks[cur][key * 64 + (((4 + quad) ^ (key & 7)) * 8)];
            f32x4 z = {0.f, 0.f, 0.f, 0.f};
            z = __builtin_amdgcn_mfma_f32_16x16x32_bf16(a0, bq0, z, 0, 0, 0);
            z = __builtin_amdgcn_mfma_f32_16x16x32_bf16(a1, bq1, z, 0, 0, 0);
            sc[g] = z;
        }
        __builtin_amdgcn_s_setprio(0);

        // boundary-only masking
        const bool needmask = (kn0 + 63 > qw + M_) || (kn0 + 63 >= klen);
        if (needmask) {
#pragma unroll
            for (int g = 0; g < 4; g++)
#pragma unroll
                for (int r = 0; r < 4; r++) {
                    int key = kn0 + g * 16 + quad * 4 + r;
                    bool valid = (key <= q + M_) && (key < klen);
                    sc[g][r] = valid ? sc[g][r] : -1e8f;
                }
        }

        // p = exp2(s): local sum, cvt_pk pack to LDS (P[q=col][key])
#pragma unroll
        for (int g = 0; g < 4; g++) {
            float pr[4];
#pragma unroll
            for (int r = 0; r < 4; r++) {
                pr[r] = __builtin_amdgcn_exp2f(sc[g][r]);
                li += pr[r];
            }
            uint2 pk;
            pk.x = cvt_pk_bf16(pr[0], pr[1]);
            pk.y = cvt_pk_bf16(pr[2], pr[3]);
            int kc = g * 2 + (quad >> 1);
            *(uint2*)&pw[col * 64 + ((kc ^ (col & 7)) * 8) + (quad & 1) * 4] = pk;
        }

        // PV swapped: A = V^T-frag (m=d), B = P-frag (n=q); D[d][q]
        bf16x8 ap0 = *(const bf16x8*)&pw[col * 64 + ((quad ^ (col & 7)) * 8)];
        bf16x8 ap1 = *(const bf16x8*)&pw[col * 64 + (((4 + quad) ^ (col & 7)) * 8)];
        __builtin_amdgcn_s_setprio(1);
#pragma unroll
        for (int g = 0; g < 4; g++) {
            int d = g * 16 + col;
            int fp = d >> 1, fo = (d & 1) * 4;
            bf16x8 bv[2];
#pragma unroll
            for (int hh = 0; hh < 2; hh++) {
                int lqA = hh * 8 + quad * 2;
                int posA = fp * 16 + (lqA ^ (fp & 15));
                int posB = fp * 16 + ((lqA + 1) ^ (fp & 15));
                u16x4 loA = *(const u16x4*)&Vs[cur][posA * 8 + fo];
                u16x4 loB = *(const u16x4*)&Vs[cur][posB * 8 + fo];
                bf16x8 t;
                t[0] = loA[0]; t[1] = loA[1]; t[2] = loA[2]; t[3] = loA[3];
                t[4] = loB[0]; t[5] = loB[1]; t[6] = loB[2]; t[7] = loB[3];
                bv[hh] = t;
            }
            o[g] = __builtin_amdgcn_mfma_f32_16x16x32_bf16(bv[0], ap0, o[g], 0, 0, 0);
            o[g] = __builtin_amdgcn_mfma_f32_16x16x32_bf16(bv[1], ap1, o[g], 0, 0, 0);
        }
        __builtin_amdgcn_s_setprio(0);
    }

    // l reduction across quads; q = col is lane-local so inv applies directly
    li += __shfl_xor(li, 16);
    li += __shfl_xor(li, 32);
    const float inv = 1.0f / li;
    const int qo = qw + col;
    if (qw + 16 <= TQ_) {
#pragma unroll
        for (int g = 0; g < 4; g++) {
            uint2 pk;
            pk.x = cvt_pk_bf16(o[g][0] * inv, o[g][1] * inv);
            pk.y = cvt_pk_bf16(o[g][2] * inv, o[g][3] * inv);
            *(uint2*)&attnb[((size_t)qo * B_ + b) * D_ + h * DH_ + g * 16 + quad * 4] = pk;
        }
    }
}

// ---------------------------------------------------------------------------
extern "C" void kernel_launch(void* const* d_in, const int* in_sizes, int n_in,
                              void* d_out, int out_size, void* d_ws, size_t ws_size,
                              hipStream_t stream)
{
    const float* utt  = (const float*)d_in[0];
    const int*   len  = (const int*)  d_in[1];
    const float* rc   = (const float*)d_in[2];
    const float* smr  = (const float*)d_in[3];
    const float* mems = (const float*)d_in[4];
    const float* Wq   = (const float*)d_in[6];
    const float* bq   = (const float*)d_in[7];
    const float* Wkv  = (const float*)d_in[8];
    const float* bkv  = (const float*)d_in[9];
    const float* Wo   = (const float*)d_in[10];
    const float* bo   = (const float*)d_in[11];

    char* ws = (char*)d_ws;
    size_t off = 0;
    auto alloc = [&](size_t bytes) -> void* {
        void* p = ws + off;
        off += (bytes + 255) & ~(size_t)255;
        return p;
    };
    u16* xall = (u16*)alloc((size_t)17408 * D_ * 2);
    u16* wq   = (u16*)alloc((size_t)D_ * D_ * 2);
    u16* wkv  = (u16*)alloc((size_t)2 * D_ * D_ * 2);
    u16* wo   = (u16*)alloc((size_t)D_ * D_ * 2);
    u16* qb   = (u16*)alloc((size_t)NROW * D_ * 2);
    u16* kb   = (u16*)alloc((size_t)NROW * D_ * 2);
    u16* vt   = (u16*)alloc((size_t)B_ * LQ_ * 512 * 4 * 2 + 65536);
    u16* attnb = xall;  // xall dead after QKV-GEMM

    k_convert4<<<2048, 256, 0, stream>>>((const float4*)utt, (const float4*)rc,
                                         (const float4*)smr, (const float4*)mems,
                                         (const float4*)Wq, (const float4*)Wkv,
                                         (const float4*)Wo,
                                         (u16x4*)xall,
                                         (u16x4*)wq, (u16x4*)wkv, (u16x4*)wo);
    k_gemm_qkv9<<<134 * 12, 256, 0, stream>>>(xall, wq, wkv, bq, bkv, qb, kb, vt);
    k_attn5<<<17 * 128, 256, 0, stream>>>(qb, kb, vt, len, attnb);
    k_gemm_o9<<<134 * 4, 256, 0, stream>>>(attnb, wo, bo, (float*)d_out);
}

// Round 9
// 200.062 us; speedup vs baseline: 1.1077x; 1.0498x over previous
//
#include <hip/hip_runtime.h>

// Problem constants (Emformer layer)
#define T_   1024
#define B_   16
#define D_   512
#define H_   8
#define R_   32
#define S_   16
#define M_   16
#define TQ_  1072          // R + T + S
#define KL_  1072          // M + R + T
#define DH_  64            // D/H
#define NROW 17152         // TQ*B == KL*B
#define K_   512           // inner dim for ALL three GEMMs
#define LQ_  268           // KL/4 (key-quad groups)
#define QSCALE 0.18033688f // 0.125 * log2(e): folded into Q projection

typedef unsigned short u16;
using bf16x8 = __attribute__((ext_vector_type(8))) short;
using bf16x4 = __attribute__((ext_vector_type(4))) short;
using f32x4  = __attribute__((ext_vector_type(4))) float;
using u16x4  = __attribute__((ext_vector_type(4))) unsigned short;

__device__ __forceinline__ u16 f2bf(float f) {
    unsigned int u = __builtin_bit_cast(unsigned int, f);
    unsigned int r = u + 0x7fffu + ((u >> 16) & 1u);
    return (u16)(r >> 16);
}

// pack 2 f32 -> 2 bf16 in one u32 (RTNE), T12 recipe
__device__ __forceinline__ unsigned int cvt_pk_bf16(float a, float b) {
    unsigned int r;
    asm("v_cvt_pk_bf16_f32 %0, %1, %2" : "=v"(r) : "v"(a), "v"(b));
    return r;
}

// 16x16x16 bf16 MFMA (A,B = 4 bf16 each): lets PV consume the QK output's
// natural 4-keys-per-lane granularity -- P stays in registers, no LDS trip.
__device__ __forceinline__ f32x4 mfma16(bf16x4 a, bf16x4 b, f32x4 c) {
    asm("v_mfma_f32_16x16x16_bf16 %0, %1, %2, %0" : "+v"(c) : "v"(a), "v"(b));
    return c;
}

// async global->LDS, 16B per lane; LDS dest = wave-uniform base + lane*16
__device__ __forceinline__ void gload_lds16(const u16* g, u16* l) {
    __builtin_amdgcn_global_load_lds(
        (const __attribute__((address_space(1))) unsigned int*)g,
        (__attribute__((address_space(3))) unsigned int*)l,
        16, 0, 0);
}

// bijective XCD swizzle (m204): hw bid -> logical wgid; same-XCD bids get a
// contiguous logical range so L2-shared operands stay on one XCD.
__device__ __forceinline__ int xcd_swz(int bid, int nwg) {
    const int q = nwg >> 3, r = nwg & 7;
    const int xcd = bid & 7, idx = bid >> 3;
    return (xcd < r ? xcd * (q + 1) : r * (q + 1) + (xcd - r) * q) + idx;
}

// ---------------------------------------------------------------------------
// Stage 1: single gathered buffer xall = [mems | rc | utt | smr] (17408 rows)
//   xkv = xall[0:17152], xq = xall[256:17408]
// ---------------------------------------------------------------------------
__global__ void k_convert4(const float4* __restrict__ utt, const float4* __restrict__ rc,
                           const float4* __restrict__ smr, const float4* __restrict__ mems,
                           const float4* __restrict__ Wq, const float4* __restrict__ Wkv,
                           const float4* __restrict__ Wo,
                           u16x4* __restrict__ xall,
                           u16x4* __restrict__ wq, u16x4* __restrict__ wkv,
                           u16x4* __restrict__ wo)
{
    const int N4 = 17408 * D_ / 4;
    const int MB = M_ * B_ * D_ / 4;
    const int RB = MB + R_ * B_ * D_ / 4;
    const int UB = RB + T_ * B_ * D_ / 4;
    const int W1 = D_ * D_ / 4, W2 = 2 * D_ * D_ / 4;
    for (int i = blockIdx.x * blockDim.x + threadIdx.x; i < N4;
         i += gridDim.x * blockDim.x) {
        float4 v;
        if (i < MB)      v = mems[i];
        else if (i < RB) v = rc[i - MB];
        else if (i < UB) v = utt[i - RB];
        else             v = smr[i - UB];
        xall[i] = (u16x4){f2bf(v.x), f2bf(v.y), f2bf(v.z), f2bf(v.w)};
        if (i < W1) { v = Wq[i];  wq[i]  = (u16x4){f2bf(v.x), f2bf(v.y), f2bf(v.z), f2bf(v.w)}; }
        if (i < W2) { v = Wkv[i]; wkv[i] = (u16x4){f2bf(v.x), f2bf(v.y), f2bf(v.z), f2bf(v.w)}; }
        if (i < W1) { v = Wo[i];  wo[i]  = (u16x4){f2bf(v.x), f2bf(v.y), f2bf(v.z), f2bf(v.w)}; }
    }
}

// ---------------------------------------------------------------------------
// m97-structure GEMM core: 256 thr / 4 waves, 128x128 tile, BK=64, SINGLE
// 32 KB LDS buffer (passed in; shared by both template instantiations),
// 2-barrier k-loop, 5 blocks/CU (m114/m97 cross-block latency hiding).
// Wave w owns rows [w*32, w*32+32) x all 128 cols: acc 2(M) x 8(N).
// Rows are 64 u16 = 8 chunks of 8; chunk c of row r at slot c^(r&7).
//   TOR=false: acc[mi*8+ni] = mfma(aF,bF): D rows = X-rows (quad*4+r)
//   TOR=true : acc[ni*2+mi] = mfma(bF,aF): D rows = W-cols (quad*4+r)
// ---------------------------------------------------------------------------
template<bool TOR>
__device__ __forceinline__ void core128(const u16* __restrict__ Ab,
                                        const u16* __restrict__ Wb,
                                        u16* As, u16* Bs, f32x4* acc)
{
    const int tid  = threadIdx.x;
    const int w    = tid >> 6, lane = tid & 63;
    const int col  = lane & 15, quad = lane >> 4;
    const int sr   = tid >> 3;                 // 0..31 staging row in round
    const int sc   = (tid & 7) ^ (sr & 7);     // pre-swizzled source chunk
    const u16* gA  = Ab + (size_t)sr * K_ + sc * 8;
    const u16* gB  = Wb + (size_t)sr * K_ + sc * 8;

#pragma unroll
    for (int i = 0; i < 16; i++) acc[i] = (f32x4){0.f, 0.f, 0.f, 0.f};

    for (int kt = 0; kt < 8; ++kt) {
        __syncthreads();                       // readers done with buffer
#pragma unroll
        for (int i = 0; i < 4; i++)            // A: 128 rows, 4 rounds of 32
            gload_lds16(gA + (size_t)(i * 32) * K_ + kt * 64,
                        &As[(i * 32 + w * 8) * 64]);
#pragma unroll
        for (int i = 0; i < 4; i++)            // B: 128 rows, 4 rounds of 32
            gload_lds16(gB + (size_t)(i * 32) * K_ + kt * 64,
                        &Bs[(i * 32 + w * 8) * 64]);
        __syncthreads();                       // tile visible (vmcnt drain)
#pragma unroll
        for (int kh = 0; kh < 2; ++kh) {
            bf16x8 aF[2], bF[8];
#pragma unroll
            for (int mi = 0; mi < 2; mi++)
                aF[mi] = *(const bf16x8*)&As[(w * 32 + mi * 16 + col) * 64
                             + (((kh * 4 + quad) ^ (col & 7)) * 8)];
#pragma unroll
            for (int ni = 0; ni < 8; ni++)
                bF[ni] = *(const bf16x8*)&Bs[(ni * 16 + col) * 64
                             + (((kh * 4 + quad) ^ (col & 7)) * 8)];
            if (TOR) {
#pragma unroll
                for (int ni = 0; ni < 8; ni++)
#pragma unroll
                    for (int mi = 0; mi < 2; mi++)
                        acc[ni * 2 + mi] = __builtin_amdgcn_mfma_f32_16x16x32_bf16(
                            bF[ni], aF[mi], acc[ni * 2 + mi], 0, 0, 0);
            } else {
#pragma unroll
                for (int mi = 0; mi < 2; mi++)
#pragma unroll
                    for (int ni = 0; ni < 8; ni++)
                        acc[mi * 8 + ni] = __builtin_amdgcn_mfma_f32_16x16x32_bf16(
                            aF[mi], bF[ni], acc[mi * 8 + ni], 0, 0, 0);
            }
        }
    }
}

// ---------------------------------------------------------------------------
// Merged Q+KV projection. Logical wgid (XCD-swizzled, tn-minor): tn 0..3 ->
// Q, 4..7 -> K, 8..11 -> V (128-col tiles); tm 0..133 (128-row tiles).
// ---------------------------------------------------------------------------
__global__ __launch_bounds__(256, 4)
void k_gemm_qkv9(const u16* __restrict__ xall,
                 const u16* __restrict__ wqp, const u16* __restrict__ wkvp,
                 const float* __restrict__ bq, const float* __restrict__ bkv,
                 u16* __restrict__ qb, u16* __restrict__ kb, u16* __restrict__ vt)
{
    __shared__ __align__(16) u16 As[128 * 64];
    __shared__ __align__(16) u16 Bs[128 * 64];

    const int wgid = xcd_swz(blockIdx.x, 134 * 12);
    const int tn = wgid % 12, tm = wgid / 12;
    const int typ = tn >> 2, sub = tn & 3;    // 0=Q, 1=K, 2=V
    const u16* Ab = (typ == 0 ? xall + (size_t)256 * K_ : xall)
                    + (size_t)tm * 128 * K_;
    const u16* Wb = (typ == 0 ? wqp : wkvp + (typ == 2 ? (size_t)512 * K_ : 0))
                    + (size_t)sub * 128 * K_;

    const int tid = threadIdx.x;
    const int w = tid >> 6, lane = tid & 63;
    const int col = lane & 15, quad = lane >> 4;

    f32x4 acc[16];
    if (typ == 2) {
        core128<false>(Ab, Wb, As, Bs, acc);
        // V -> vt[b][l/4][f][4]; l = tm*8 + w*2 + mi; b = quad*4+r
        const int lq = tm * 2 + (w >> 1);
        const int so = (w & 1) * 2;           // l%4 = so + mi
#pragma unroll
        for (int ni = 0; ni < 8; ni++) {
            const int f = sub * 128 + ni * 16 + col;
            const float bs = bkv[512 + f];
#pragma unroll
            for (int r = 0; r < 4; r++) {
                const int bb = quad * 4 + r;
                unsigned int pk = cvt_pk_bf16(acc[0 * 8 + ni][r] + bs,
                                              acc[1 * 8 + ni][r] + bs);
                *(unsigned int*)&vt[(((size_t)bb * LQ_ + lq) * 512 + f) * 4 + so] = pk;
            }
        }
    } else {
        core128<true>(Ab, Wb, As, Bs, acc);
        const float* bias = (typ == 0) ? bq : bkv;
        u16* outp = (typ == 0) ? qb : kb;
        const float qs = (typ == 0) ? QSCALE : 1.0f;
#pragma unroll
        for (int ni = 0; ni < 8; ni++) {
            const int gc0 = sub * 128 + ni * 16 + quad * 4;
            const float4 bs4 = *(const float4*)&bias[gc0];
#pragma unroll
            for (int mi = 0; mi < 2; mi++) {
                const int mrow = tm * 128 + w * 32 + mi * 16 + col;
                f32x4 a = acc[ni * 2 + mi];
                uint2 pk;
                pk.x = cvt_pk_bf16((a[0] + bs4.x) * qs, (a[1] + bs4.y) * qs);
                pk.y = cvt_pk_bf16((a[2] + bs4.z) * qs, (a[3] + bs4.w) * qs);
                *(uint2*)&outp[(size_t)mrow * 512 + gc0] = pk;
            }
        }
    }
}

// ---------------------------------------------------------------------------
// Output projection + clip/slice epilogue (fp32 out), TOR core, float4 stores.
// ---------------------------------------------------------------------------
__global__ __launch_bounds__(256, 4)
void k_gemm_o9(const u16* __restrict__ A, const u16* __restrict__ W,
               const float* __restrict__ bias, float* __restrict__ Co)
{
    __shared__ __align__(16) u16 As[128 * 64];
    __shared__ __align__(16) u16 Bs[128 * 64];

    const int wgid = xcd_swz(blockIdx.x, 134 * 4);
    const int tn = wgid % 4, tm = wgid / 4;
    const u16* Ab = A + (size_t)tm * 128 * K_;
    const u16* Wb = W + (size_t)tn * 128 * K_;

    const int tid = threadIdx.x;
    const int w = tid >> 6, lane = tid & 63;
    const int col = lane & 15, quad = lane >> 4;

    f32x4 acc[16];
    core128<true>(Ab, Wb, As, Bs, acc);

#pragma unroll
    for (int ni = 0; ni < 8; ni++) {
        const int gc0 = tn * 128 + ni * 16 + quad * 4;
        const float4 bs4 = *(const float4*)&bias[gc0];
#pragma unroll
        for (int mi = 0; mi < 2; mi++) {
            const int l = tm * 8 + w * 2 + mi;
            if (l == TQ_ - 1) continue;
            const int mrow = tm * 128 + w * 32 + mi * 16 + col;
            f32x4 a = acc[ni * 2 + mi];
            float4 v = {a[0] + bs4.x, a[1] + bs4.y, a[2] + bs4.z, a[3] + bs4.w};
            if (l >= TQ_ - S_) {
                v.x = fminf(10.0f, fmaxf(-10.0f, v.x));
                v.y = fminf(10.0f, fmaxf(-10.0f, v.y));
                v.z = fminf(10.0f, fmaxf(-10.0f, v.z));
                v.w = fminf(10.0f, fmaxf(-10.0f, v.w));
            }
            *(float4*)&Co[(size_t)mrow * 512 + gc0] = v;
        }
    }
}

// ---------------------------------------------------------------------------
// Flash attention v7: PV via 16x16x16 MFMA so the P-fragment is the lane's
// OWN cvt_pk output (keys quad*4+r) -- no Ps LDS, no P round-trip, no V
// register packing (one u16x4 per A-frag). LDS 40->32 KB => 5 blocks/CU.
// QK^T, masking, staging, epilogue identical to the verified v6.
// ---------------------------------------------------------------------------
__global__ __launch_bounds__(256, 4)
void k_attn5(const u16* __restrict__ qbuf, const u16* __restrict__ kb,
             const u16* __restrict__ vt, const int* __restrict__ lenp,
             u16* __restrict__ attnb)
{
    __shared__ __align__(16) u16 Ks[2][64 * 64];
    __shared__ __align__(16) u16 Vs[2][64 * 64];

    const int blk  = blockIdx.x;
    const int qblk = 16 - (blk >> 7);       // heavy (qblk=16) first
    const int bh   = blk & 127;             // blk%8 == h -> head pinned to XCD
    const int b = bh >> 3, h = bh & 7;
    const int tid = threadIdx.x;
    const int w = tid >> 6, lane = tid & 63;
    const int col = lane & 15, quad = lane >> 4;

    int stride = (lenp[1] == 0) ? 2 : 1;
    int maxlen = 0;
    for (int i = 0; i < B_; i++) maxlen = max(maxlen, lenp[i * stride]);
    const int klen = lenp[b * stride] + M_ + (TQ_ - maxlen - S_);

    const int q0 = qblk * 64;
    const int qw = q0 + w * 16;
    const int q  = qw + col;

    int qrow = min(q, TQ_ - 1);
    const u16* qp = qbuf + ((size_t)qrow * B_ + b) * D_ + h * DH_ + quad * 8;
    bf16x8 bq0 = *(const bf16x8*)(qp);
    bf16x8 bq1 = *(const bf16x8*)(qp + 32);

    const int s0 = tid, s1 = tid + 256;
    const u16* kbase = kb + (size_t)b * 512 + h * DH_;
    size_t kof0 = (size_t)(s0 >> 3) * 8192 + (size_t)(((s0 & 7) ^ ((s0 >> 3) & 7)) * 8);
    size_t kof1 = (size_t)(s1 >> 3) * 8192 + (size_t)(((s1 & 7) ^ ((s1 >> 3) & 7)) * 8);
    const u16* vbase = vt + ((size_t)b * LQ_ * 512 + (size_t)h * DH_) * 4;
    auto vchunk = [](int s) -> size_t {
        int fp = s >> 4;
        int lq = (s & 15) ^ (fp & 15);
        return (size_t)lq * 2048 + (size_t)fp * 8;
    };
    const size_t vof0 = vchunk(s0), vof1 = vchunk(s1);

    float li = 0.f;                         // per-lane partial sum of p (q = col)
    f32x4 o[4];
#pragma unroll
    for (int g = 0; g < 4; g++) o[g] = (f32x4){0.f, 0.f, 0.f, 0.f};

    const int nk = min(q0 + 64 + M_, klen);
    const int numkt = (nk + 63) >> 6;

    gload_lds16(kbase + kof0, &Ks[0][(size_t)w * 512]);
    gload_lds16(kbase + kof1, &Ks[0][2048 + (size_t)w * 512]);
    gload_lds16(vbase + vof0, &Vs[0][(size_t)w * 512]);
    gload_lds16(vbase + vof1, &Vs[0][2048 + (size_t)w * 512]);

    for (int kt = 0; kt < numkt; kt++) {
        const int kn0 = kt * 64;
        const int cur = kt & 1;
        __syncthreads();
        if (kt + 1 < numkt) {
            const size_t kstep = (size_t)(kn0 + 64) * 8192;
            const size_t vstep = (size_t)(kt + 1) * 32768;
            gload_lds16(kbase + kstep + kof0, &Ks[cur ^ 1][(size_t)w * 512]);
            gload_lds16(kbase + kstep + kof1, &Ks[cur ^ 1][2048 + (size_t)w * 512]);
            gload_lds16(vbase + vstep + vof0, &Vs[cur ^ 1][(size_t)w * 512]);
            gload_lds16(vbase + vstep + vof1, &Vs[cur ^ 1][2048 + (size_t)w * 512]);
        }

        // QK^T (Q pre-scaled into exp2 domain): sc[g][r] = S[kn0+g*16+quad*4+r][q=col]
        f32x4 sc[4];
        __builtin_amdgcn_s_setprio(1);
#pragma unroll
        for (int g = 0; g < 4; g++) {
            int key = g * 16 + col;
            bf16x8 a0 = *(const bf16x8*)&Ks[cur][key * 64 + ((quad ^ (key & 7)) * 8)];
            bf16x8 a1 = *(const bf16x8*)&Ks[cur][key * 64 + (((4 + quad) ^ (key & 7)) * 8)];
            f32x4 z = {0.f, 0.f, 0.f, 0.f};
            z = __builtin_amdgcn_mfma_f32_16x16x32_bf16(a0, bq0, z, 0, 0, 0);
            z = __builtin_amdgcn_mfma_f32_16x16x32_bf16(a1, bq1, z, 0, 0, 0);
            sc[g] = z;
        }
        __builtin_amdgcn_s_setprio(0);

        // boundary-only masking
        const bool needmask = (kn0 + 63 > qw + M_) || (kn0 + 63 >= klen);
        if (needmask) {
#pragma unroll
            for (int g = 0; g < 4; g++)
#pragma unroll
                for (int r = 0; r < 4; r++) {
                    int key = kn0 + g * 16 + quad * 4 + r;
                    bool valid = (key <= q + M_) && (key < klen);
                    sc[g][r] = valid ? sc[g][r] : -1e8f;
                }
        }

        // p = exp2(s): tree-summed per g, packed in-register as bf16x4
        // pk[g] = P[q=col][keys g*16 + quad*4 + 0..3] == the 16x16x16 B-frag.
        bf16x4 pk[4];
#pragma unroll
        for (int g = 0; g < 4; g++) {
            float pr[4];
#pragma unroll
            for (int r = 0; r < 4; r++)
                pr[r] = __builtin_amdgcn_exp2f(sc[g][r]);
            li += (pr[0] + pr[1]) + (pr[2] + pr[3]);
            uint2 pku;
            pku.x = cvt_pk_bf16(pr[0], pr[1]);
            pku.y = cvt_pk_bf16(pr[2], pr[3]);
            pk[g] = __builtin_bit_cast(bf16x4, pku);
        }

        // PV: o[g] += sum_ks mfma16(V-frag, pk[ks]); D[d=g*16+quad*4+r][q=col]
        // V-frag for (ks,g): V[ks*16+quad*4+j][d=g*16+col] = one u16x4 from
        // vt chunk (lq=ks*4+quad, fp=d>>1) at halfword offset (d&1)*4.
        __builtin_amdgcn_s_setprio(1);
#pragma unroll
        for (int g = 0; g < 4; g++) {
            const int d  = g * 16 + col;
            const int fp = d >> 1, fo = (d & 1) * 4;
#pragma unroll
            for (int ks = 0; ks < 4; ks++) {
                const int lq  = ks * 4 + quad;
                const int pos = fp * 16 + (lq ^ (fp & 15));
                bf16x4 av = __builtin_bit_cast(bf16x4,
                    *(const u16x4*)&Vs[cur][pos * 8 + fo]);
                o[g] = mfma16(av, pk[ks], o[g]);
            }
        }
        __builtin_amdgcn_s_setprio(0);
    }

    // l reduction across quads; q = col is lane-local so inv applies directly
    li += __shfl_xor(li, 16);
    li += __shfl_xor(li, 32);
    const float inv = 1.0f / li;
    const int qo = qw + col;
    if (qw + 16 <= TQ_) {
#pragma unroll
        for (int g = 0; g < 4; g++) {
            uint2 pkk;
            pkk.x = cvt_pk_bf16(o[g][0] * inv, o[g][1] * inv);
            pkk.y = cvt_pk_bf16(o[g][2] * inv, o[g][3] * inv);
            *(uint2*)&attnb[((size_t)qo * B_ + b) * D_ + h * DH_ + g * 16 + quad * 4] = pkk;
        }
    }
}

// ---------------------------------------------------------------------------
extern "C" void kernel_launch(void* const* d_in, const int* in_sizes, int n_in,
                              void* d_out, int out_size, void* d_ws, size_t ws_size,
                              hipStream_t stream)
{
    const float* utt  = (const float*)d_in[0];
    const int*   len  = (const int*)  d_in[1];
    const float* rc   = (const float*)d_in[2];
    const float* smr  = (const float*)d_in[3];
    const float* mems = (const float*)d_in[4];
    const float* Wq   = (const float*)d_in[6];
    const float* bq   = (const float*)d_in[7];
    const float* Wkv  = (const float*)d_in[8];
    const float* bkv  = (const float*)d_in[9];
    const float* Wo   = (const float*)d_in[10];
    const float* bo   = (const float*)d_in[11];

    char* ws = (char*)d_ws;
    size_t off = 0;
    auto alloc = [&](size_t bytes) -> void* {
        void* p = ws + off;
        off += (bytes + 255) & ~(size_t)255;
        return p;
    };
    u16* xall = (u16*)alloc((size_t)17408 * D_ * 2);
    u16* wq   = (u16*)alloc((size_t)D_ * D_ * 2);
    u16* wkv  = (u16*)alloc((size_t)2 * D_ * D_ * 2);
    u16* wo   = (u16*)alloc((size_t)D_ * D_ * 2);
    u16* qb   = (u16*)alloc((size_t)NROW * D_ * 2);
    u16* kb   = (u16*)alloc((size_t)NROW * D_ * 2);
    u16* vt   = (u16*)alloc((size_t)B_ * LQ_ * 512 * 4 * 2 + 65536);
    u16* attnb = xall;  // xall dead after QKV-GEMM

    k_convert4<<<2048, 256, 0, stream>>>((const float4*)utt, (const float4*)rc,
                                         (const float4*)smr, (const float4*)mems,
                                         (const float4*)Wq, (const float4*)Wkv,
                                         (const float4*)Wo,
                                         (u16x4*)xall,
                                         (u16x4*)wq, (u16x4*)wkv, (u16x4*)wo);
    k_gemm_qkv9<<<134 * 12, 256, 0, stream>>>(xall, wq, wkv, bq, bkv, qb, kb, vt);
    k_attn5<<<17 * 128, 256, 0, stream>>>(qb, kb, vt, len, attnb);
    k_gemm_o9<<<134 * 4, 256, 0, stream>>>(attnb, wo, bo, (float*)d_out);
}